// Round 8
// baseline (691.014 us; speedup 1.0000x reference)
//
#include <hip/hip_runtime.h>
#include <hip/hip_bf16.h>
#include <hip/hip_fp16.h>
#include <math.h>

// Problem constants: B=32, L=128, D=6, T=63, V=50000, E=C=128, H=256
#define NV 50000
#define NC 128
#define NH 256
#define NB 32
#define NL 128
#define NT 63
#define G3 768   // 3*H

typedef _Float16 f16x8 __attribute__((ext_vector_type(8)));
typedef _Float16 f16x2 __attribute__((ext_vector_type(2)));
typedef float f32x4 __attribute__((ext_vector_type(4)));

__device__ __forceinline__ void unpk4_(uint2 u, float f[4]) {
  f16x2 a = __builtin_bit_cast(f16x2, u.x);
  f16x2 b = __builtin_bit_cast(f16x2, u.y);
  f[0] = (float)a[0]; f[1] = (float)a[1];
  f[2] = (float)b[0]; f[3] = (float)b[1];
}

// ---------------------------------------------------------------------------
// C[m][n] = sum_k A[m][k]*B[n][k] (+bias), K=128, f32 out (for P = emb@Wc^T).
// ---------------------------------------------------------------------------
__global__ __launch_bounds__(256) void gemm_bt_k128(
    const float* __restrict__ A, const float* __restrict__ Bm,
    const float* __restrict__ bias, float* __restrict__ Cm,
    int M, int N) {
  __shared__ __align__(16) float As[64 * 129];
  __shared__ __align__(16) float BsT[64 * 132];  // [kk][n], one k-half
  const int m0 = blockIdx.x * 64;
  const int n0 = blockIdx.y * 128;
  const int tid = threadIdx.x;

#pragma unroll
  for (int i = 0; i < 32; ++i) {
    int e = tid + i * 256;
    int r = e >> 7, k = e & 127;
    int m = m0 + r;
    As[r * 129 + k] = (m < M) ? A[(size_t)m * 128 + k] : 0.0f;
  }

  const int tn = tid & 15;
  const int tm = tid >> 4;
  const int ml = tm * 4, nl = tn * 8;

  float acc[4][8];
#pragma unroll
  for (int i = 0; i < 4; ++i)
#pragma unroll
    for (int j = 0; j < 8; ++j) acc[i][j] = 0.0f;

#pragma unroll
  for (int h = 0; h < 2; ++h) {
    if (h) __syncthreads();
#pragma unroll
    for (int i = 0; i < 32; ++i) {
      int e = tid + i * 256;
      int n = e >> 6, kk = e & 63;
      BsT[kk * 132 + n] = Bm[(size_t)(n0 + n) * 128 + h * 64 + kk];
    }
    __syncthreads();
#pragma unroll 4
    for (int kk = 0; kk < 64; ++kk) {
      const int k = h * 64 + kk;
      float a0 = As[(ml + 0) * 129 + k];
      float a1 = As[(ml + 1) * 129 + k];
      float a2 = As[(ml + 2) * 129 + k];
      float a3 = As[(ml + 3) * 129 + k];
      float4 b0 = *(const float4*)&BsT[kk * 132 + nl];
      float4 b1 = *(const float4*)&BsT[kk * 132 + nl + 4];
      const float bv[8] = {b0.x, b0.y, b0.z, b0.w, b1.x, b1.y, b1.z, b1.w};
#pragma unroll
      for (int j = 0; j < 8; ++j) {
        acc[0][j] = fmaf(a0, bv[j], acc[0][j]);
        acc[1][j] = fmaf(a1, bv[j], acc[1][j]);
        acc[2][j] = fmaf(a2, bv[j], acc[2][j]);
        acc[3][j] = fmaf(a3, bv[j], acc[3][j]);
      }
    }
  }

  float bv[8];
#pragma unroll
  for (int j = 0; j < 8; ++j) bv[j] = bias ? bias[n0 + nl + j] : 0.0f;

#pragma unroll
  for (int i = 0; i < 4; ++i) {
    int m = m0 + ml + i;
    if (m < M) {
      float* crow = &Cm[(size_t)m * N + n0 + nl];
#pragma unroll
      for (int j = 0; j < 8; ++j) crow[j] = acc[i][j] + bv[j];
    }
  }
}

// ---------------------------------------------------------------------------
// GI GEMM: A = enc [4096][128], B = Wih_{f,b} [768][128] (z = dir), bias bih.
// Output written DIRECTLY in the scan's f16 gate-lane layout:
//   GIp[((dir*2+bg)*128 + t)*3*16*256 + (rs*16 + nb)*256 + c]   (f16)
// with m = b*128+t, bg=b>>4, nb=b&15, col = rs*256+c.
// ---------------------------------------------------------------------------
__global__ __launch_bounds__(256) void gemm_gi(
    const float* __restrict__ A,
    const float* __restrict__ B0, const float* __restrict__ B1,
    const float* __restrict__ bias0, const float* __restrict__ bias1,
    unsigned short* __restrict__ GIp, int M, int N) {
  const float* __restrict__ Bm = blockIdx.z ? B1 : B0;
  const float* __restrict__ bias = blockIdx.z ? bias1 : bias0;

  __shared__ __align__(16) float As[64 * 129];
  __shared__ __align__(16) float BsT[64 * 132];
  const int m0 = blockIdx.x * 64;
  const int n0 = blockIdx.y * 128;
  const int tid = threadIdx.x;

#pragma unroll
  for (int i = 0; i < 32; ++i) {
    int e = tid + i * 256;
    int r = e >> 7, k = e & 127;
    int m = m0 + r;
    As[r * 129 + k] = (m < M) ? A[(size_t)m * 128 + k] : 0.0f;
  }

  const int tn = tid & 15;
  const int tm = tid >> 4;
  const int ml = tm * 4, nl = tn * 8;

  float acc[4][8];
#pragma unroll
  for (int i = 0; i < 4; ++i)
#pragma unroll
    for (int j = 0; j < 8; ++j) acc[i][j] = 0.0f;

#pragma unroll
  for (int h = 0; h < 2; ++h) {
    if (h) __syncthreads();
#pragma unroll
    for (int i = 0; i < 32; ++i) {
      int e = tid + i * 256;
      int n = e >> 6, kk = e & 63;
      BsT[kk * 132 + n] = Bm[(size_t)(n0 + n) * 128 + h * 64 + kk];
    }
    __syncthreads();
#pragma unroll 4
    for (int kk = 0; kk < 64; ++kk) {
      const int k = h * 64 + kk;
      float a0 = As[(ml + 0) * 129 + k];
      float a1 = As[(ml + 1) * 129 + k];
      float a2 = As[(ml + 2) * 129 + k];
      float a3 = As[(ml + 3) * 129 + k];
      float4 b0 = *(const float4*)&BsT[kk * 132 + nl];
      float4 b1 = *(const float4*)&BsT[kk * 132 + nl + 4];
      const float bv[8] = {b0.x, b0.y, b0.z, b0.w, b1.x, b1.y, b1.z, b1.w};
#pragma unroll
      for (int j = 0; j < 8; ++j) {
        acc[0][j] = fmaf(a0, bv[j], acc[0][j]);
        acc[1][j] = fmaf(a1, bv[j], acc[1][j]);
        acc[2][j] = fmaf(a2, bv[j], acc[2][j]);
        acc[3][j] = fmaf(a3, bv[j], acc[3][j]);
      }
    }
  }

  float bv[8];
#pragma unroll
  for (int j = 0; j < 8; ++j) bv[j] = bias[n0 + nl + j];

  const int ncol = n0 + nl;            // multiple of 8; no rs straddle
  const int rs = ncol >> 8;
  const int cc = ncol & 255;
#pragma unroll
  for (int i = 0; i < 4; ++i) {
    int m = m0 + ml + i;
    if (m < M) {
      int b = m >> 7, t = m & 127;
      int bg = b >> 4, nb = b & 15;
      unsigned short hs[8];
#pragma unroll
      for (int j = 0; j < 8; ++j) {
        _Float16 hv = (_Float16)(acc[i][j] + bv[j]);
        hs[j] = __builtin_bit_cast(unsigned short, hv);
      }
      uint4 ov;
      ov.x = (unsigned)hs[0] | ((unsigned)hs[1] << 16);
      ov.y = (unsigned)hs[2] | ((unsigned)hs[3] << 16);
      ov.z = (unsigned)hs[4] | ((unsigned)hs[5] << 16);
      ov.w = (unsigned)hs[6] | ((unsigned)hs[7] << 16);
      size_t didx = ((((size_t)(blockIdx.z * 2 + bg) * 128 + t) * 3 + rs) * 16 + nb) * 256 + cc;
      *(uint4*)&GIp[didx] = ov;
    }
  }
}

// ---------------------------------------------------------------------------
// Tree encode: per (b,l), heap-sum P[tok], + cnt*bc, max, relu.
// ---------------------------------------------------------------------------
__global__ __launch_bounds__(128) void tree_encode(
    const int* __restrict__ tokens, const float* __restrict__ P,
    const float* __restrict__ bc, float* __restrict__ enc) {
  __shared__ int toks[NT];
  const int blk = blockIdx.x;
  const int c = threadIdx.x;
  if (c < NT) toks[c] = tokens[(size_t)blk * NT + c];
  __syncthreads();

  float s[NT];
#pragma unroll
  for (int i = 0; i < NT; ++i) s[i] = P[(size_t)toks[i] * NC + c];
#pragma unroll
  for (int i = 30; i >= 0; --i) s[i] += s[2 * i + 1] + s[2 * i + 2];

  const float bcv = bc[c];
  float m = -1e30f;
#pragma unroll
  for (int i = 0; i < NT; ++i) {
    const float cnt = (i == 0) ? 63.0f
                    : (i < 3)  ? 31.0f
                    : (i < 7)  ? 15.0f
                    : (i < 15) ? 7.0f
                    : (i < 31) ? 3.0f
                               : 1.0f;
    m = fmaxf(m, s[i] + cnt * bcv);
  }
  enc[(size_t)blk * NC + c] = fmaxf(m, 0.0f);
}

// ---------------------------------------------------------------------------
// Pack Whh f32 [768][256] -> MFMA A-fragments (f16):
//   Apk[(((dir*16 + w)*3 + mt)*8 + ks)*64 + lane] = uint4 of 8 f16:
//     Wrow = 16*w + 256*mt + (lane&15),  k(j) = ks*32 + (lane>>4)*8 + j
// (Same slot->k map as the scan's B-read: any consistent bijection is valid.)
// ---------------------------------------------------------------------------
__global__ __launch_bounds__(256) void conv_w_pack(
    const float* __restrict__ Wf, const float* __restrict__ Wb,
    uint4* __restrict__ Apk) {
  int i = blockIdx.x * 256 + threadIdx.x;  // [0, 2*16*3*8*64)
  if (i >= 2 * 16 * 3 * 8 * 64) return;
  const int dir = i / 24576;
  int rem = i - dir * 24576;
  const int w = rem / 1536; rem -= w * 1536;
  const int mt = rem / 512; rem -= mt * 512;
  const int ks = rem >> 6;
  const int lane = rem & 63;
  const int Wrow = 16 * w + 256 * mt + (lane & 15);
  const int k0 = ks * 32 + ((lane >> 4) << 3);
  const float* __restrict__ W = dir ? Wb : Wf;
  const float4 a = *(const float4*)&W[(size_t)Wrow * NH + k0];
  const float4 b = *(const float4*)&W[(size_t)Wrow * NH + k0 + 4];
  const float v[8] = {a.x, a.y, a.z, a.w, b.x, b.y, b.z, b.w};
  unsigned short hs[8];
#pragma unroll
  for (int j = 0; j < 8; ++j) {
    _Float16 hv = (_Float16)v[j];
    hs[j] = __builtin_bit_cast(unsigned short, hv);
  }
  uint4 o;
  o.x = (unsigned)hs[0] | ((unsigned)hs[1] << 16);
  o.y = (unsigned)hs[2] | ((unsigned)hs[3] << 16);
  o.z = (unsigned)hs[4] | ((unsigned)hs[5] << 16);
  o.w = (unsigned)hs[6] | ((unsigned)hs[7] << 16);
  Apk[i] = o;
}

// ---------------------------------------------------------------------------
// GRU scan via MFMA. 4 blocks (dir x 2 batch-groups of 16) x 1024 threads
// (16 waves). Per step: GH[768x16] = Whh @ H via 16x16x32 f16 MFMA; wave w
// owns M-tiles {w, w+16, w+32} (= r/z/n rows of channels [16w,16w+16)) so
// gates are lane-local on the D fragments (D: col=lane&15=batch,
// row=(lane>>4)*4+q). W lives in 24 uint4/thread of MFMA operands ->
// AGPR/VGPR unified file (393KB/CU = whole W_dir), loaded ONCE.
// h kept as f16 in LDS [16 batch][264], rebuilt into B-frags per step.
// ---------------------------------------------------------------------------
__global__ __launch_bounds__(1024) void gru_scan_mfma(
    const uint4* __restrict__ Apk, const unsigned short* __restrict__ GIp,
    const float* __restrict__ bhh_f, const float* __restrict__ bhh_b,
    float* __restrict__ out) {
  const int dir = blockIdx.x >> 1;
  const int bg = blockIdx.x & 1;
  const int tid = threadIdx.x;
  const int w = tid >> 6;
  const int lane = tid & 63;
  const int lg = lane >> 4;
  const int nb = lane & 15;               // batch col within group
  const int c0 = (w << 4) + (lg << 2);    // first of this lane's 4 channels

  __shared__ __align__(16) unsigned short hT[2][16][264];

  // One-time W fragment load (coalesced; 24 uint4 = 96 regs -> unified RF).
  uint4 wfr[24];
#pragma unroll
  for (int mt = 0; mt < 3; ++mt)
#pragma unroll
    for (int ks = 0; ks < 8; ++ks)
      wfr[mt * 8 + ks] =
          Apk[((((size_t)dir * 16 + w) * 3 + mt) * 8 + ks) * 64 + lane];

  const float* __restrict__ bhh = dir ? bhh_b : bhh_f;
  float bR[4], bZ[4], bN[4];
  {
    float4 r4 = *(const float4*)&bhh[0 * NH + c0];
    float4 z4 = *(const float4*)&bhh[1 * NH + c0];
    float4 n4 = *(const float4*)&bhh[2 * NH + c0];
    bR[0] = r4.x; bR[1] = r4.y; bR[2] = r4.z; bR[3] = r4.w;
    bZ[0] = z4.x; bZ[1] = z4.y; bZ[2] = z4.z; bZ[3] = z4.w;
    bN[0] = n4.x; bN[1] = n4.y; bN[2] = n4.z; bN[3] = n4.w;
  }

  // Zero h buffer 0.
  for (int i = tid; i < 16 * 264; i += 1024) ((unsigned short*)hT)[i] = 0;

  const unsigned short* __restrict__ gi_blk =
      GIp + (size_t)((dir * 2 + bg) * 128) * 12288;  // per-t slice = 3*16*256
  const int t0 = dir ? NL - 1 : 0;
  uint2 giR = *(const uint2*)(gi_blk + (size_t)t0 * 12288 + (0 * 16 + nb) * 256 + c0);
  uint2 giZ = *(const uint2*)(gi_blk + (size_t)t0 * 12288 + (1 * 16 + nb) * 256 + c0);
  uint2 giN = *(const uint2*)(gi_blk + (size_t)t0 * 12288 + (2 * 16 + nb) * 256 + c0);

  float hq[4] = {0.f, 0.f, 0.f, 0.f};
  float hmax[4] = {-1e30f, -1e30f, -1e30f, -1e30f};
  __syncthreads();

  for (int st = 0; st < NL; ++st) {
    // B fragments from current h buffer (k = ks*32 + lg*8 + j).
    uint4 bfr[8];
    const unsigned short* hrow = &hT[st & 1][nb][lg << 3];
#pragma unroll
    for (int ks = 0; ks < 8; ++ks)
      bfr[ks] = *(const uint4*)(hrow + ks * 32);

    // Prefetch next step's gi (hides under MFMA).
    const int stn = (st + 1 < NL) ? st + 1 : st;
    const int tn = dir ? (NL - 1 - stn) : stn;
    uint2 giRn = *(const uint2*)(gi_blk + (size_t)tn * 12288 + (0 * 16 + nb) * 256 + c0);
    uint2 giZn = *(const uint2*)(gi_blk + (size_t)tn * 12288 + (1 * 16 + nb) * 256 + c0);
    uint2 giNn = *(const uint2*)(gi_blk + (size_t)tn * 12288 + (2 * 16 + nb) * 256 + c0);

    // GH = W @ H : 3 gate tiles x 8 K-steps.
    f32x4 aR = {0.f, 0.f, 0.f, 0.f}, aZ = aR, aN = aR;
#pragma unroll
    for (int ks = 0; ks < 8; ++ks) {
      f16x8 bv = __builtin_bit_cast(f16x8, bfr[ks]);
      aR = __builtin_amdgcn_mfma_f32_16x16x32_f16(
          __builtin_bit_cast(f16x8, wfr[ks]), bv, aR, 0, 0, 0);
      aZ = __builtin_amdgcn_mfma_f32_16x16x32_f16(
          __builtin_bit_cast(f16x8, wfr[8 + ks]), bv, aZ, 0, 0, 0);
      aN = __builtin_amdgcn_mfma_f32_16x16x32_f16(
          __builtin_bit_cast(f16x8, wfr[16 + ks]), bv, aN, 0, 0, 0);
    }

    // Gates, lane-local: channel c0+q, batch nb.
    float gr[4], gz[4], gn[4];
    unpk4_(giR, gr); unpk4_(giZ, gz); unpk4_(giN, gn);
    unsigned short h16[4];
#pragma unroll
    for (int q = 0; q < 4; ++q) {
      float r = __builtin_amdgcn_rcpf(1.f + __expf(-(gr[q] + aR[q] + bR[q])));
      float z = __builtin_amdgcn_rcpf(1.f + __expf(-(gz[q] + aZ[q] + bZ[q])));
      float x = gn[q] + r * (aN[q] + bN[q]);
      float e = __expf(-2.f * x);
      float n = 2.f * __builtin_amdgcn_rcpf(1.f + e) - 1.f;  // tanh(x)
      hq[q] = (1.f - z) * n + z * hq[q];
      hmax[q] = fmaxf(hmax[q], hq[q]);
      _Float16 hv = (_Float16)hq[q];
      h16[q] = __builtin_bit_cast(unsigned short, hv);
    }
    // Write h_new (4 consecutive f16 = one 8B store).
    uint2 hw;
    hw.x = (unsigned)h16[0] | ((unsigned)h16[1] << 16);
    hw.y = (unsigned)h16[2] | ((unsigned)h16[3] << 16);
    *(uint2*)&hT[(st + 1) & 1][nb][c0] = hw;
    __syncthreads();
    giR = giRn; giZ = giZn; giN = giNn;
  }

  // Output: out[b][dir*256 + c], b = bg*16 + nb.
  float4 o = {hmax[0], hmax[1], hmax[2], hmax[3]};
  *(float4*)&out[(size_t)(bg * 16 + nb) * (2 * NH) + dir * NH + c0] = o;
}

// ---------------------------------------------------------------------------
extern "C" void kernel_launch(void* const* d_in, const int* in_sizes, int n_in,
                              void* d_out, int out_size, void* d_ws, size_t ws_size,
                              hipStream_t stream) {
  const int*   tokens = (const int*)d_in[0];
  const float* emb    = (const float*)d_in[1];
  const float* Wc     = (const float*)d_in[2];
  const float* bc     = (const float*)d_in[3];
  const float* Wih_f  = (const float*)d_in[4];
  const float* Whh_f  = (const float*)d_in[5];
  const float* bih_f  = (const float*)d_in[6];
  const float* bhh_f  = (const float*)d_in[7];
  const float* Wih_b  = (const float*)d_in[8];
  const float* Whh_b  = (const float*)d_in[9];
  const float* bih_b  = (const float*)d_in[10];
  const float* bhh_b  = (const float*)d_in[11];
  float* out = (float*)d_out;

  // Workspace (f32 units): P[50000*128] | enc[4096*128] | GIp (4.72M f16)
  //                        | Apk (49152 uint4)
  float* P   = (float*)d_ws;
  float* enc = P + (size_t)NV * NC;                       // +6,400,000
  unsigned short* GIp = (unsigned short*)(enc + (size_t)NB * NL * NC);
  uint4* Apk = (uint4*)(GIp + (size_t)2 * 2 * 128 * 3 * 16 * 256);

  // 0) Pack Whh -> MFMA A-fragments.
  conv_w_pack<<<dim3(192), dim3(256), 0, stream>>>(Whh_f, Whh_b, Apk);
  // 1) P = emb @ Wc^T   (V x C)
  gemm_bt_k128<<<dim3((NV + 63) / 64, NC / 128), dim3(256), 0, stream>>>(
      emb, Wc, nullptr, P, NV, NC);
  // 2) tree encode -> enc (B*L x C)
  tree_encode<<<dim3(NB * NL), dim3(128), 0, stream>>>(tokens, P, bc, enc);
  // 3) GI f+b, written directly in the scan's f16 layout.
  gemm_gi<<<dim3(NB * NL / 64, G3 / 128, 2), dim3(256), 0, stream>>>(
      enc, Wih_f, Wih_b, bih_f, bih_b, GIp, NB * NL, G3);
  // 4) GRU scan via MFMA (W in unified AGPR/VGPR file).
  gru_scan_mfma<<<dim3(4), dim3(1024), 0, stream>>>(
      Apk, GIp, bhh_f, bhh_b, out);
}

// Round 10
// 525.025 us; speedup vs baseline: 1.3162x; 1.3162x over previous
//
#include <hip/hip_runtime.h>
#include <hip/hip_bf16.h>
#include <hip/hip_fp16.h>
#include <math.h>

// Problem constants: B=32, L=128, D=6, T=63, V=50000, E=C=128, H=256
#define NV 50000
#define NC 128
#define NH 256
#define NB 32
#define NL 128
#define NT 63
#define G3 768   // 3*H

typedef _Float16 f16x8 __attribute__((ext_vector_type(8)));
typedef _Float16 f16x2 __attribute__((ext_vector_type(2)));
typedef float f32x4 __attribute__((ext_vector_type(4)));

__device__ __forceinline__ float h2f_(unsigned int u, int hi) {
  f16x2 p = __builtin_bit_cast(f16x2, u);
  return (float)p[hi];
}

// ---------------------------------------------------------------------------
// C[m][n] = sum_k A[m][k]*B[n][k] (+bias), K=128, f32 out (for P = emb@Wc^T).
// ---------------------------------------------------------------------------
__global__ __launch_bounds__(256) void gemm_bt_k128(
    const float* __restrict__ A, const float* __restrict__ Bm,
    const float* __restrict__ bias, float* __restrict__ Cm,
    int M, int N) {
  __shared__ __align__(16) float As[64 * 129];
  __shared__ __align__(16) float BsT[64 * 132];  // [kk][n], one k-half
  const int m0 = blockIdx.x * 64;
  const int n0 = blockIdx.y * 128;
  const int tid = threadIdx.x;

#pragma unroll
  for (int i = 0; i < 32; ++i) {
    int e = tid + i * 256;
    int r = e >> 7, k = e & 127;
    int m = m0 + r;
    As[r * 129 + k] = (m < M) ? A[(size_t)m * 128 + k] : 0.0f;
  }

  const int tn = tid & 15;
  const int tm = tid >> 4;
  const int ml = tm * 4, nl = tn * 8;

  float acc[4][8];
#pragma unroll
  for (int i = 0; i < 4; ++i)
#pragma unroll
    for (int j = 0; j < 8; ++j) acc[i][j] = 0.0f;

#pragma unroll
  for (int h = 0; h < 2; ++h) {
    if (h) __syncthreads();
#pragma unroll
    for (int i = 0; i < 32; ++i) {
      int e = tid + i * 256;
      int n = e >> 6, kk = e & 63;
      BsT[kk * 132 + n] = Bm[(size_t)(n0 + n) * 128 + h * 64 + kk];
    }
    __syncthreads();
#pragma unroll 4
    for (int kk = 0; kk < 64; ++kk) {
      const int k = h * 64 + kk;
      float a0 = As[(ml + 0) * 129 + k];
      float a1 = As[(ml + 1) * 129 + k];
      float a2 = As[(ml + 2) * 129 + k];
      float a3 = As[(ml + 3) * 129 + k];
      float4 b0 = *(const float4*)&BsT[kk * 132 + nl];
      float4 b1 = *(const float4*)&BsT[kk * 132 + nl + 4];
      const float bv[8] = {b0.x, b0.y, b0.z, b0.w, b1.x, b1.y, b1.z, b1.w};
#pragma unroll
      for (int j = 0; j < 8; ++j) {
        acc[0][j] = fmaf(a0, bv[j], acc[0][j]);
        acc[1][j] = fmaf(a1, bv[j], acc[1][j]);
        acc[2][j] = fmaf(a2, bv[j], acc[2][j]);
        acc[3][j] = fmaf(a3, bv[j], acc[3][j]);
      }
    }
  }

  float bv[8];
#pragma unroll
  for (int j = 0; j < 8; ++j) bv[j] = bias ? bias[n0 + nl + j] : 0.0f;

#pragma unroll
  for (int i = 0; i < 4; ++i) {
    int m = m0 + ml + i;
    if (m < M) {
      float* crow = &Cm[(size_t)m * N + n0 + nl];
#pragma unroll
      for (int j = 0; j < 8; ++j) crow[j] = acc[i][j] + bv[j];
    }
  }
}

// ---------------------------------------------------------------------------
// GI GEMM: A = enc [4096][128], B = Wih_{f,b} [768][128] (z = dir).
// bias = bih + bhh for the r,z gates (n<512) — folded so the scan needs no
// per-step r/z bias adds. Output written in the scan's f16 gate-lane layout:
//   GIp[((dir*2+bg)*128 + t)*12288 + (rs*16 + nb)*256 + c]
// ---------------------------------------------------------------------------
__global__ __launch_bounds__(256) void gemm_gi(
    const float* __restrict__ A,
    const float* __restrict__ B0, const float* __restrict__ B1,
    const float* __restrict__ bias0, const float* __restrict__ bias1,
    const float* __restrict__ bh0, const float* __restrict__ bh1,
    unsigned short* __restrict__ GIp, int M, int N) {
  const float* __restrict__ Bm = blockIdx.z ? B1 : B0;
  const float* __restrict__ bias = blockIdx.z ? bias1 : bias0;
  const float* __restrict__ bh = blockIdx.z ? bh1 : bh0;

  __shared__ __align__(16) float As[64 * 129];
  __shared__ __align__(16) float BsT[64 * 132];
  const int m0 = blockIdx.x * 64;
  const int n0 = blockIdx.y * 128;
  const int tid = threadIdx.x;

#pragma unroll
  for (int i = 0; i < 32; ++i) {
    int e = tid + i * 256;
    int r = e >> 7, k = e & 127;
    int m = m0 + r;
    As[r * 129 + k] = (m < M) ? A[(size_t)m * 128 + k] : 0.0f;
  }

  const int tn = tid & 15;
  const int tm = tid >> 4;
  const int ml = tm * 4, nl = tn * 8;

  float acc[4][8];
#pragma unroll
  for (int i = 0; i < 4; ++i)
#pragma unroll
    for (int j = 0; j < 8; ++j) acc[i][j] = 0.0f;

#pragma unroll
  for (int h = 0; h < 2; ++h) {
    if (h) __syncthreads();
#pragma unroll
    for (int i = 0; i < 32; ++i) {
      int e = tid + i * 256;
      int n = e >> 6, kk = e & 63;
      BsT[kk * 132 + n] = Bm[(size_t)(n0 + n) * 128 + h * 64 + kk];
    }
    __syncthreads();
#pragma unroll 4
    for (int kk = 0; kk < 64; ++kk) {
      const int k = h * 64 + kk;
      float a0 = As[(ml + 0) * 129 + k];
      float a1 = As[(ml + 1) * 129 + k];
      float a2 = As[(ml + 2) * 129 + k];
      float a3 = As[(ml + 3) * 129 + k];
      float4 b0 = *(const float4*)&BsT[kk * 132 + nl];
      float4 b1 = *(const float4*)&BsT[kk * 132 + nl + 4];
      const float bv[8] = {b0.x, b0.y, b0.z, b0.w, b1.x, b1.y, b1.z, b1.w};
#pragma unroll
      for (int j = 0; j < 8; ++j) {
        acc[0][j] = fmaf(a0, bv[j], acc[0][j]);
        acc[1][j] = fmaf(a1, bv[j], acc[1][j]);
        acc[2][j] = fmaf(a2, bv[j], acc[2][j]);
        acc[3][j] = fmaf(a3, bv[j], acc[3][j]);
      }
    }
  }

  float bv[8];
#pragma unroll
  for (int j = 0; j < 8; ++j) {
    const int n = n0 + nl + j;
    bv[j] = bias[n] + (n < 512 ? bh[n] : 0.0f);  // fold bhh_r, bhh_z
  }

  const int ncol = n0 + nl;
  const int rs = ncol >> 8;
  const int cc = ncol & 255;
#pragma unroll
  for (int i = 0; i < 4; ++i) {
    int m = m0 + ml + i;
    if (m < M) {
      int b = m >> 7, t = m & 127;
      int bg = b >> 4, nb = b & 15;
      unsigned short hs[8];
#pragma unroll
      for (int j = 0; j < 8; ++j) {
        _Float16 hv = (_Float16)(acc[i][j] + bv[j]);
        hs[j] = __builtin_bit_cast(unsigned short, hv);
      }
      uint4 ov;
      ov.x = (unsigned)hs[0] | ((unsigned)hs[1] << 16);
      ov.y = (unsigned)hs[2] | ((unsigned)hs[3] << 16);
      ov.z = (unsigned)hs[4] | ((unsigned)hs[5] << 16);
      ov.w = (unsigned)hs[6] | ((unsigned)hs[7] << 16);
      size_t didx =
          ((((size_t)(blockIdx.z * 2 + bg) * 128 + t) * 3 + rs) * 16 + nb) * 256 + cc;
      *(uint4*)&GIp[didx] = ov;
    }
  }
}

// ---------------------------------------------------------------------------
// Tree encode: per (b,l), heap-sum P[tok], + cnt*bc, max, relu.
// ---------------------------------------------------------------------------
__global__ __launch_bounds__(128) void tree_encode(
    const int* __restrict__ tokens, const float* __restrict__ P,
    const float* __restrict__ bc, float* __restrict__ enc) {
  __shared__ int toks[NT];
  const int blk = blockIdx.x;
  const int c = threadIdx.x;
  if (c < NT) toks[c] = tokens[(size_t)blk * NT + c];
  __syncthreads();

  float s[NT];
#pragma unroll
  for (int i = 0; i < NT; ++i) s[i] = P[(size_t)toks[i] * NC + c];
#pragma unroll
  for (int i = 30; i >= 0; --i) s[i] += s[2 * i + 1] + s[2 * i + 2];

  const float bcv = bc[c];
  float m = -1e30f;
#pragma unroll
  for (int i = 0; i < NT; ++i) {
    const float cnt = (i == 0) ? 63.0f
                    : (i < 3)  ? 31.0f
                    : (i < 7)  ? 15.0f
                    : (i < 15) ? 7.0f
                    : (i < 31) ? 3.0f
                               : 1.0f;
    m = fmaxf(m, s[i] + cnt * bcv);
  }
  enc[(size_t)blk * NC + c] = fmaxf(m, 0.0f);
}

// ---------------------------------------------------------------------------
// Pack Whh f32 [768][256] -> MFMA A-fragments (f16), LAYOUT VERIFIED in R8:
//   Apk[(((dir*16 + cs)*3 + mt)*8 + ks)*64 + lane]:
//     Wrow = 16*cs + 256*mt + (lane&15),  k(j) = ks*32 + (lane>>4)*8 + j
// ---------------------------------------------------------------------------
__global__ __launch_bounds__(256) void conv_w_pack(
    const float* __restrict__ Wf, const float* __restrict__ Wb,
    uint4* __restrict__ Apk) {
  int i = blockIdx.x * 256 + threadIdx.x;  // [0, 2*16*3*8*64)
  if (i >= 2 * 16 * 3 * 8 * 64) return;
  const int dir = i / 24576;
  int rem = i - dir * 24576;
  const int cs = rem / 1536; rem -= cs * 1536;
  const int mt = rem / 512; rem -= mt * 512;
  const int ks = rem >> 6;
  const int lane = rem & 63;
  const int Wrow = 16 * cs + 256 * mt + (lane & 15);
  const int k0 = ks * 32 + ((lane >> 4) << 3);
  const float* __restrict__ W = dir ? Wb : Wf;
  const float4 a = *(const float4*)&W[(size_t)Wrow * NH + k0];
  const float4 b = *(const float4*)&W[(size_t)Wrow * NH + k0 + 4];
  const float v[8] = {a.x, a.y, a.z, a.w, b.x, b.y, b.z, b.w};
  unsigned short hs[8];
#pragma unroll
  for (int j = 0; j < 8; ++j) {
    _Float16 hv = (_Float16)v[j];
    hs[j] = __builtin_bit_cast(unsigned short, hv);
  }
  uint4 o;
  o.x = (unsigned)hs[0] | ((unsigned)hs[1] << 16);
  o.y = (unsigned)hs[2] | ((unsigned)hs[3] << 16);
  o.z = (unsigned)hs[4] | ((unsigned)hs[5] << 16);
  o.w = (unsigned)hs[6] | ((unsigned)hs[7] << 16);
  Apk[i] = o;
}

// ---------------------------------------------------------------------------
// GRU scan v10. 4 blocks (dir x bg16) x 256 threads (4 waves, 1 wave/SIMD:
// __launch_bounds__(256,1) -> 512 unified regs/thread = 256 VGPR + 256 AGPR).
// Wave w owns channel-sets {4w..4w+3} = 12 M-tiles = 96 uint4 (384 dwords)
// of W fragments. MFMA A-operands are av-class in LLVM, so the allocator can
// (and at this budget, should) park all W in the otherwise-idle AGPR half
// and keep the ~110-dword working set in arch VGPRs — no pins, no asm, the
// same plain intrinsics whose numerics R8 verified on HW (absmax 3.9e-3).
// Per step: 96 MFMA (12 indep acc chains), gates lane-local on D fragments,
// h via double-buffered LDS, one barrier/step.
// ---------------------------------------------------------------------------
__global__ __launch_bounds__(256, 1) void gru_scan_v10(
    const uint4* __restrict__ Apk, const unsigned short* __restrict__ GIp,
    const float* __restrict__ bhh_f, const float* __restrict__ bhh_b,
    float* __restrict__ out) {
  const int dir = blockIdx.x >> 1;
  const int bg = blockIdx.x & 1;
  const int tid = threadIdx.x;
  const int w = tid >> 6;      // wave [0,4)
  const int lane = tid & 63;
  const int lg = lane >> 4;    // k-group / D-row group
  const int nb = lane & 15;    // batch col within group

  __shared__ __align__(16) unsigned short hT[2][16][264];

  // One-time W fragment fill: 96 coalesced dwordx4 loads.
  uint4 wa[96];
#pragma unroll
  for (int q = 0; q < 96; ++q) {
    const int s = q / 24, mt = (q / 8) % 3, ks = q & 7;
    wa[q] =
        Apk[((((size_t)dir * 16 + (4 * w + s)) * 3 + mt) * 8 + ks) * 64 + lane];
  }

  const float* __restrict__ bhh = dir ? bhh_b : bhh_f;
  // bhh_n for this lane's 16 channels (4 sets x 4), packed f16 (8 dwords).
  uint2 bn16[4];
#pragma unroll
  for (int s = 0; s < 4; ++s) {
    const int c0 = (4 * w + s) * 16 + (lg << 2);
    float4 b4 = *(const float4*)&bhh[2 * NH + c0];
    _Float16 h0 = (_Float16)b4.x, h1 = (_Float16)b4.y;
    _Float16 h2 = (_Float16)b4.z, h3 = (_Float16)b4.w;
    bn16[s].x = (unsigned)__builtin_bit_cast(unsigned short, h0) |
                ((unsigned)__builtin_bit_cast(unsigned short, h1) << 16);
    bn16[s].y = (unsigned)__builtin_bit_cast(unsigned short, h2) |
                ((unsigned)__builtin_bit_cast(unsigned short, h3) << 16);
  }

  // Zero h buffer 0 (2112 uints).
  for (int i = tid; i < 16 * 264 / 2; i += 256) ((unsigned int*)hT)[i] = 0u;

  const unsigned short* __restrict__ gi_blk =
      GIp + (size_t)((dir * 2 + bg) * 128) * 12288;

  float hq[16], hmax[16];
#pragma unroll
  for (int q = 0; q < 16; ++q) { hq[q] = 0.0f; hmax[q] = -1e30f; }
  __syncthreads();

  for (int st = 0; st < NL; ++st) {
    const int t = dir ? (NL - 1 - st) : st;
    const unsigned short* __restrict__ git = gi_blk + (size_t)t * 12288;

    // B fragments from current h buffer, shared by all 4 channel-sets.
    uint4 bfr[8];
    const unsigned short* hrow = &hT[st & 1][nb][lg << 3];
#pragma unroll
    for (int ks = 0; ks < 8; ++ks)
      bfr[ks] = *(const uint4*)(hrow + ks * 32);

#pragma unroll
    for (int s = 0; s < 4; ++s) {
      const int c0 = (4 * w + s) * 16 + (lg << 2);
      // gi loads issue ahead of the MFMA chain; latency hides under it.
      uint2 giR = *(const uint2*)(git + (0 * 16 + nb) * 256 + c0);
      uint2 giZ = *(const uint2*)(git + (1 * 16 + nb) * 256 + c0);
      uint2 giN = *(const uint2*)(git + (2 * 16 + nb) * 256 + c0);

      f32x4 aR = {0.f, 0.f, 0.f, 0.f};
      f32x4 aZ = {0.f, 0.f, 0.f, 0.f};
      f32x4 aN = {h2f_(bn16[s].x, 0), h2f_(bn16[s].x, 1),
                  h2f_(bn16[s].y, 0), h2f_(bn16[s].y, 1)};  // + bhh_n
#pragma unroll
      for (int ks = 0; ks < 8; ++ks) {
        f16x8 bv = __builtin_bit_cast(f16x8, bfr[ks]);
        aR = __builtin_amdgcn_mfma_f32_16x16x32_f16(
            __builtin_bit_cast(f16x8, wa[s * 24 + 0 + ks]), bv, aR, 0, 0, 0);
        aZ = __builtin_amdgcn_mfma_f32_16x16x32_f16(
            __builtin_bit_cast(f16x8, wa[s * 24 + 8 + ks]), bv, aZ, 0, 0, 0);
        aN = __builtin_amdgcn_mfma_f32_16x16x32_f16(
            __builtin_bit_cast(f16x8, wa[s * 24 + 16 + ks]), bv, aN, 0, 0, 0);
      }

      unsigned short h16[4];
#pragma unroll
      for (int q = 0; q < 4; ++q) {
        const unsigned gru = (q & 2) ? giR.y : giR.x;
        const unsigned gzu = (q & 2) ? giZ.y : giZ.x;
        const unsigned gnu = (q & 2) ? giN.y : giN.x;
        float gr = h2f_(gru, q & 1);
        float gz = h2f_(gzu, q & 1);
        float gn = h2f_(gnu, q & 1);
        float r = __builtin_amdgcn_rcpf(1.f + __expf(-(gr + aR[q])));
        float z = __builtin_amdgcn_rcpf(1.f + __expf(-(gz + aZ[q])));
        float x = gn + r * aN[q];
        float e = __expf(-2.f * x);
        float n = 2.f * __builtin_amdgcn_rcpf(1.f + e) - 1.f;  // tanh
        float hnew = (1.f - z) * n + z * hq[s * 4 + q];
        hq[s * 4 + q] = hnew;
        hmax[s * 4 + q] = fmaxf(hmax[s * 4 + q], hnew);
        _Float16 hv = (_Float16)hnew;
        h16[q] = __builtin_bit_cast(unsigned short, hv);
      }
      uint2 hw;
      hw.x = (unsigned)h16[0] | ((unsigned)h16[1] << 16);
      hw.y = (unsigned)h16[2] | ((unsigned)h16[3] << 16);
      *(uint2*)&hT[(st + 1) & 1][nb][c0] = hw;
    }
    __syncthreads();
  }

  // Output: out[b][dir*256 + c], b = bg*16 + nb.
#pragma unroll
  for (int s = 0; s < 4; ++s) {
    const int c0 = (4 * w + s) * 16 + (lg << 2);
    float4 o = {hmax[s * 4 + 0], hmax[s * 4 + 1],
                hmax[s * 4 + 2], hmax[s * 4 + 3]};
    *(float4*)&out[(size_t)(bg * 16 + nb) * (2 * NH) + dir * NH + c0] = o;
  }
}

// ---------------------------------------------------------------------------
extern "C" void kernel_launch(void* const* d_in, const int* in_sizes, int n_in,
                              void* d_out, int out_size, void* d_ws, size_t ws_size,
                              hipStream_t stream) {
  const int*   tokens = (const int*)d_in[0];
  const float* emb    = (const float*)d_in[1];
  const float* Wc     = (const float*)d_in[2];
  const float* bc     = (const float*)d_in[3];
  const float* Wih_f  = (const float*)d_in[4];
  const float* Whh_f  = (const float*)d_in[5];
  const float* bih_f  = (const float*)d_in[6];
  const float* bhh_f  = (const float*)d_in[7];
  const float* Wih_b  = (const float*)d_in[8];
  const float* Whh_b  = (const float*)d_in[9];
  const float* bih_b  = (const float*)d_in[10];
  const float* bhh_b  = (const float*)d_in[11];
  float* out = (float*)d_out;

  // Workspace (f32 units): P[50000*128] | enc[4096*128] | GIp (6.29M f16)
  //                        | Apk (49152 uint4)
  float* P   = (float*)d_ws;
  float* enc = P + (size_t)NV * NC;
  unsigned short* GIp = (unsigned short*)(enc + (size_t)NB * NL * NC);
  uint4* Apk = (uint4*)(GIp + (size_t)2 * 2 * 128 * 3 * 16 * 256);

  // 0) Pack Whh -> MFMA A-fragments.
  conv_w_pack<<<dim3(192), dim3(256), 0, stream>>>(Whh_f, Whh_b, Apk);
  // 1) P = emb @ Wc^T   (V x C)
  gemm_bt_k128<<<dim3((NV + 63) / 64, NC / 128), dim3(256), 0, stream>>>(
      emb, Wc, nullptr, P, NV, NC);
  // 2) tree encode -> enc (B*L x C)
  tree_encode<<<dim3(NB * NL), dim3(128), 0, stream>>>(tokens, P, bc, enc);
  // 3) GI f+b, f16 scan layout, bhh_r/z folded.
  gemm_gi<<<dim3(NB * NL / 64, G3 / 128, 2), dim3(256), 0, stream>>>(
      enc, Wih_f, Wih_b, bih_f, bih_b, bhh_f, bhh_b, GIp, NB * NL, G3);
  // 4) GRU scan v10 — W in the unified RF via 1-wave/SIMD budget.
  gru_scan_v10<<<dim3(4), dim3(256), 0, stream>>>(
      Apk, GIp, bhh_f, bhh_b, out);
}

// Round 11
// 510.622 us; speedup vs baseline: 1.3533x; 1.0282x over previous
//
#include <hip/hip_runtime.h>
#include <hip/hip_bf16.h>
#include <hip/hip_fp16.h>
#include <math.h>

// Problem constants: B=32, L=128, D=6, T=63, V=50000, E=C=128, H=256
#define NV 50000
#define NC 128
#define NH 256
#define NB 32
#define NL 128
#define NT 63
#define G3 768   // 3*H

typedef _Float16 f16x8 __attribute__((ext_vector_type(8)));
typedef _Float16 f16x2 __attribute__((ext_vector_type(2)));
typedef float f32x4 __attribute__((ext_vector_type(4)));

__device__ __forceinline__ float h2f_(unsigned int u, int hi) {
  f16x2 p = __builtin_bit_cast(f16x2, u);
  return (float)p[hi];
}

// ---------------------------------------------------------------------------
// C[m][n] = sum_k A[m][k]*B[n][k] (+bias), K=128, f32 out (for P = emb@Wc^T).
// ---------------------------------------------------------------------------
__global__ __launch_bounds__(256) void gemm_bt_k128(
    const float* __restrict__ A, const float* __restrict__ Bm,
    const float* __restrict__ bias, float* __restrict__ Cm,
    int M, int N) {
  __shared__ __align__(16) float As[64 * 129];
  __shared__ __align__(16) float BsT[64 * 132];  // [kk][n], one k-half
  const int m0 = blockIdx.x * 64;
  const int n0 = blockIdx.y * 128;
  const int tid = threadIdx.x;

#pragma unroll
  for (int i = 0; i < 32; ++i) {
    int e = tid + i * 256;
    int r = e >> 7, k = e & 127;
    int m = m0 + r;
    As[r * 129 + k] = (m < M) ? A[(size_t)m * 128 + k] : 0.0f;
  }

  const int tn = tid & 15;
  const int tm = tid >> 4;
  const int ml = tm * 4, nl = tn * 8;

  float acc[4][8];
#pragma unroll
  for (int i = 0; i < 4; ++i)
#pragma unroll
    for (int j = 0; j < 8; ++j) acc[i][j] = 0.0f;

#pragma unroll
  for (int h = 0; h < 2; ++h) {
    if (h) __syncthreads();
#pragma unroll
    for (int i = 0; i < 32; ++i) {
      int e = tid + i * 256;
      int n = e >> 6, kk = e & 63;
      BsT[kk * 132 + n] = Bm[(size_t)(n0 + n) * 128 + h * 64 + kk];
    }
    __syncthreads();
#pragma unroll 4
    for (int kk = 0; kk < 64; ++kk) {
      const int k = h * 64 + kk;
      float a0 = As[(ml + 0) * 129 + k];
      float a1 = As[(ml + 1) * 129 + k];
      float a2 = As[(ml + 2) * 129 + k];
      float a3 = As[(ml + 3) * 129 + k];
      float4 b0 = *(const float4*)&BsT[kk * 132 + nl];
      float4 b1 = *(const float4*)&BsT[kk * 132 + nl + 4];
      const float bv[8] = {b0.x, b0.y, b0.z, b0.w, b1.x, b1.y, b1.z, b1.w};
#pragma unroll
      for (int j = 0; j < 8; ++j) {
        acc[0][j] = fmaf(a0, bv[j], acc[0][j]);
        acc[1][j] = fmaf(a1, bv[j], acc[1][j]);
        acc[2][j] = fmaf(a2, bv[j], acc[2][j]);
        acc[3][j] = fmaf(a3, bv[j], acc[3][j]);
      }
    }
  }

  float bv[8];
#pragma unroll
  for (int j = 0; j < 8; ++j) bv[j] = bias ? bias[n0 + nl + j] : 0.0f;

#pragma unroll
  for (int i = 0; i < 4; ++i) {
    int m = m0 + ml + i;
    if (m < M) {
      float* crow = &Cm[(size_t)m * N + n0 + nl];
#pragma unroll
      for (int j = 0; j < 8; ++j) crow[j] = acc[i][j] + bv[j];
    }
  }
}

// ---------------------------------------------------------------------------
// GI GEMM: A = enc [4096][128], B = Wih_{f,b} [768][128] (z = dir).
// bias = bih + bhh for the r,z gates (n<512). Output in the scan's f16
// gate-lane layout: GIp[((dir*2+bg)*128 + t)*12288 + (rs*16 + nb)*256 + c]
// ---------------------------------------------------------------------------
__global__ __launch_bounds__(256) void gemm_gi(
    const float* __restrict__ A,
    const float* __restrict__ B0, const float* __restrict__ B1,
    const float* __restrict__ bias0, const float* __restrict__ bias1,
    const float* __restrict__ bh0, const float* __restrict__ bh1,
    unsigned short* __restrict__ GIp, int M, int N) {
  const float* __restrict__ Bm = blockIdx.z ? B1 : B0;
  const float* __restrict__ bias = blockIdx.z ? bias1 : bias0;
  const float* __restrict__ bh = blockIdx.z ? bh1 : bh0;

  __shared__ __align__(16) float As[64 * 129];
  __shared__ __align__(16) float BsT[64 * 132];
  const int m0 = blockIdx.x * 64;
  const int n0 = blockIdx.y * 128;
  const int tid = threadIdx.x;

#pragma unroll
  for (int i = 0; i < 32; ++i) {
    int e = tid + i * 256;
    int r = e >> 7, k = e & 127;
    int m = m0 + r;
    As[r * 129 + k] = (m < M) ? A[(size_t)m * 128 + k] : 0.0f;
  }

  const int tn = tid & 15;
  const int tm = tid >> 4;
  const int ml = tm * 4, nl = tn * 8;

  float acc[4][8];
#pragma unroll
  for (int i = 0; i < 4; ++i)
#pragma unroll
    for (int j = 0; j < 8; ++j) acc[i][j] = 0.0f;

#pragma unroll
  for (int h = 0; h < 2; ++h) {
    if (h) __syncthreads();
#pragma unroll
    for (int i = 0; i < 32; ++i) {
      int e = tid + i * 256;
      int n = e >> 6, kk = e & 63;
      BsT[kk * 132 + n] = Bm[(size_t)(n0 + n) * 128 + h * 64 + kk];
    }
    __syncthreads();
#pragma unroll 4
    for (int kk = 0; kk < 64; ++kk) {
      const int k = h * 64 + kk;
      float a0 = As[(ml + 0) * 129 + k];
      float a1 = As[(ml + 1) * 129 + k];
      float a2 = As[(ml + 2) * 129 + k];
      float a3 = As[(ml + 3) * 129 + k];
      float4 b0 = *(const float4*)&BsT[kk * 132 + nl];
      float4 b1 = *(const float4*)&BsT[kk * 132 + nl + 4];
      const float bv[8] = {b0.x, b0.y, b0.z, b0.w, b1.x, b1.y, b1.z, b1.w};
#pragma unroll
      for (int j = 0; j < 8; ++j) {
        acc[0][j] = fmaf(a0, bv[j], acc[0][j]);
        acc[1][j] = fmaf(a1, bv[j], acc[1][j]);
        acc[2][j] = fmaf(a2, bv[j], acc[2][j]);
        acc[3][j] = fmaf(a3, bv[j], acc[3][j]);
      }
    }
  }

  float bv[8];
#pragma unroll
  for (int j = 0; j < 8; ++j) {
    const int n = n0 + nl + j;
    bv[j] = bias[n] + (n < 512 ? bh[n] : 0.0f);  // fold bhh_r, bhh_z
  }

  const int ncol = n0 + nl;
  const int rs = ncol >> 8;
  const int cc = ncol & 255;
#pragma unroll
  for (int i = 0; i < 4; ++i) {
    int m = m0 + ml + i;
    if (m < M) {
      int b = m >> 7, t = m & 127;
      int bg = b >> 4, nb = b & 15;
      unsigned short hs[8];
#pragma unroll
      for (int j = 0; j < 8; ++j) {
        _Float16 hv = (_Float16)(acc[i][j] + bv[j]);
        hs[j] = __builtin_bit_cast(unsigned short, hv);
      }
      uint4 ov;
      ov.x = (unsigned)hs[0] | ((unsigned)hs[1] << 16);
      ov.y = (unsigned)hs[2] | ((unsigned)hs[3] << 16);
      ov.z = (unsigned)hs[4] | ((unsigned)hs[5] << 16);
      ov.w = (unsigned)hs[6] | ((unsigned)hs[7] << 16);
      size_t didx =
          ((((size_t)(blockIdx.z * 2 + bg) * 128 + t) * 3 + rs) * 16 + nb) * 256 + cc;
      *(uint4*)&GIp[didx] = ov;
    }
  }
}

// ---------------------------------------------------------------------------
// Tree encode: per (b,l), heap-sum P[tok], + cnt*bc, max, relu.
// ---------------------------------------------------------------------------
__global__ __launch_bounds__(128) void tree_encode(
    const int* __restrict__ tokens, const float* __restrict__ P,
    const float* __restrict__ bc, float* __restrict__ enc) {
  __shared__ int toks[NT];
  const int blk = blockIdx.x;
  const int c = threadIdx.x;
  if (c < NT) toks[c] = tokens[(size_t)blk * NT + c];
  __syncthreads();

  float s[NT];
#pragma unroll
  for (int i = 0; i < NT; ++i) s[i] = P[(size_t)toks[i] * NC + c];
#pragma unroll
  for (int i = 30; i >= 0; --i) s[i] += s[2 * i + 1] + s[2 * i + 2];

  const float bcv = bc[c];
  float m = -1e30f;
#pragma unroll
  for (int i = 0; i < NT; ++i) {
    const float cnt = (i == 0) ? 63.0f
                    : (i < 3)  ? 31.0f
                    : (i < 7)  ? 15.0f
                    : (i < 15) ? 7.0f
                    : (i < 31) ? 3.0f
                               : 1.0f;
    m = fmaxf(m, s[i] + cnt * bcv);
  }
  enc[(size_t)blk * NC + c] = fmaxf(m, 0.0f);
}

// ---------------------------------------------------------------------------
// Pack Whh f32 [768][256] -> MFMA A-fragments (f16), LAYOUT VERIFIED in R8:
//   Apk[(((dir*16 + cs)*3 + mt)*8 + ks)*64 + lane]:
//     Wrow = 16*cs + 256*mt + (lane&15),  k(j) = ks*32 + (lane>>4)*8 + j
// ---------------------------------------------------------------------------
__global__ __launch_bounds__(256) void conv_w_pack(
    const float* __restrict__ Wf, const float* __restrict__ Wb,
    uint4* __restrict__ Apk) {
  int i = blockIdx.x * 256 + threadIdx.x;  // [0, 2*16*3*8*64)
  if (i >= 2 * 16 * 3 * 8 * 64) return;
  const int dir = i / 24576;
  int rem = i - dir * 24576;
  const int cs = rem / 1536; rem -= cs * 1536;
  const int mt = rem / 512; rem -= mt * 512;
  const int ks = rem >> 6;
  const int lane = rem & 63;
  const int Wrow = 16 * cs + 256 * mt + (lane & 15);
  const int k0 = ks * 32 + ((lane >> 4) << 3);
  const float* __restrict__ W = dir ? Wb : Wf;
  const float4 a = *(const float4*)&W[(size_t)Wrow * NH + k0];
  const float4 b = *(const float4*)&W[(size_t)Wrow * NH + k0 + 4];
  const float v[8] = {a.x, a.y, a.z, a.w, b.x, b.y, b.z, b.w};
  unsigned short hs[8];
#pragma unroll
  for (int j = 0; j < 8; ++j) {
    _Float16 hv = (_Float16)v[j];
    hs[j] = __builtin_bit_cast(unsigned short, hv);
  }
  uint4 o;
  o.x = (unsigned)hs[0] | ((unsigned)hs[1] << 16);
  o.y = (unsigned)hs[2] | ((unsigned)hs[3] << 16);
  o.z = (unsigned)hs[4] | ((unsigned)hs[5] << 16);
  o.w = (unsigned)hs[6] | ((unsigned)hs[7] << 16);
  Apk[i] = o;
}

// ---------------------------------------------------------------------------
// GRU scan v11 = v10 + SCALAR ASM PINS on all 384 W dwords.
// 4 blocks (dir x bg16) x 256 threads (4 waves, 1 wave/SIMD -> 512 unified
// regs/thread = 256 VGPR + 256 AGPR). The pins (compile-proven form from v7)
// make the loaded W values asm outputs -> the compiler CANNOT rematerialize
// the loads into the loop (v10's failure, 6144cy/step of L2 streaming).
// The only uses are MFMA A-operands (av-class: AGPR placement is free at
// use), so the allocator parks ~256 W dwords in the idle AGPR half and the
// rest + working set in arch VGPRs. No tuple ties anywhere (R9's error).
// ---------------------------------------------------------------------------
__global__ __launch_bounds__(256, 1) void gru_scan_v11(
    const uint4* __restrict__ Apk, const unsigned short* __restrict__ GIp,
    const float* __restrict__ bhh_f, const float* __restrict__ bhh_b,
    float* __restrict__ out) {
  const int dir = blockIdx.x >> 1;
  const int bg = blockIdx.x & 1;
  const int tid = threadIdx.x;
  const int w = tid >> 6;      // wave [0,4)
  const int lane = tid & 63;
  const int lg = lane >> 4;    // k-group / D-row group
  const int nb = lane & 15;    // batch col within group

  __shared__ __align__(16) unsigned short hT[2][16][264];

  // One-time W fragment fill: 96 coalesced dwordx4 loads...
  uint4 wa[96];
#pragma unroll
  for (int q = 0; q < 96; ++q) {
    const int s = q / 24, mt = (q / 8) % 3, ks = q & 7;
    wa[q] =
        Apk[((((size_t)dir * 16 + (4 * w + s)) * 3 + mt) * 8 + ks) * 64 + lane];
  }
  // ...then PIN every dword (scalar "+v": compiles — v7; blocks remat).
#pragma unroll
  for (int q = 0; q < 96; ++q) {
    asm volatile("" : "+v"(wa[q].x), "+v"(wa[q].y), "+v"(wa[q].z),
                      "+v"(wa[q].w));
  }

  const float* __restrict__ bhh = dir ? bhh_b : bhh_f;
  // bhh_n for this lane's 16 channels (4 sets x 4), packed f16 (8 dwords).
  uint2 bn16[4];
#pragma unroll
  for (int s = 0; s < 4; ++s) {
    const int c0 = (4 * w + s) * 16 + (lg << 2);
    float4 b4 = *(const float4*)&bhh[2 * NH + c0];
    _Float16 h0 = (_Float16)b4.x, h1 = (_Float16)b4.y;
    _Float16 h2 = (_Float16)b4.z, h3 = (_Float16)b4.w;
    bn16[s].x = (unsigned)__builtin_bit_cast(unsigned short, h0) |
                ((unsigned)__builtin_bit_cast(unsigned short, h1) << 16);
    bn16[s].y = (unsigned)__builtin_bit_cast(unsigned short, h2) |
                ((unsigned)__builtin_bit_cast(unsigned short, h3) << 16);
  }

  // Zero h buffer 0 (2112 uints).
  for (int i = tid; i < 16 * 264 / 2; i += 256) ((unsigned int*)hT)[i] = 0u;

  const unsigned short* __restrict__ gi_blk =
      GIp + (size_t)((dir * 2 + bg) * 128) * 12288;

  float hq[16], hmax[16];
#pragma unroll
  for (int q = 0; q < 16; ++q) { hq[q] = 0.0f; hmax[q] = -1e30f; }
  __syncthreads();

  for (int st = 0; st < NL; ++st) {
    const int t = dir ? (NL - 1 - st) : st;
    const unsigned short* __restrict__ git = gi_blk + (size_t)t * 12288;

    // B fragments from current h buffer, shared by all 4 channel-sets.
    uint4 bfr[8];
    const unsigned short* hrow = &hT[st & 1][nb][lg << 3];
#pragma unroll
    for (int ks = 0; ks < 8; ++ks)
      bfr[ks] = *(const uint4*)(hrow + ks * 32);

#pragma unroll
    for (int s = 0; s < 4; ++s) {
      const int c0 = (4 * w + s) * 16 + (lg << 2);
      // gi loads issue ahead of the MFMA chain; latency hides under it.
      uint2 giR = *(const uint2*)(git + (0 * 16 + nb) * 256 + c0);
      uint2 giZ = *(const uint2*)(git + (1 * 16 + nb) * 256 + c0);
      uint2 giN = *(const uint2*)(git + (2 * 16 + nb) * 256 + c0);

      f32x4 aR = {0.f, 0.f, 0.f, 0.f};
      f32x4 aZ = {0.f, 0.f, 0.f, 0.f};
      f32x4 aN = {h2f_(bn16[s].x, 0), h2f_(bn16[s].x, 1),
                  h2f_(bn16[s].y, 0), h2f_(bn16[s].y, 1)};  // + bhh_n
#pragma unroll
      for (int ks = 0; ks < 8; ++ks) {
        f16x8 bv = __builtin_bit_cast(f16x8, bfr[ks]);
        aR = __builtin_amdgcn_mfma_f32_16x16x32_f16(
            __builtin_bit_cast(f16x8, wa[s * 24 + 0 + ks]), bv, aR, 0, 0, 0);
        aZ = __builtin_amdgcn_mfma_f32_16x16x32_f16(
            __builtin_bit_cast(f16x8, wa[s * 24 + 8 + ks]), bv, aZ, 0, 0, 0);
        aN = __builtin_amdgcn_mfma_f32_16x16x32_f16(
            __builtin_bit_cast(f16x8, wa[s * 24 + 16 + ks]), bv, aN, 0, 0, 0);
      }

      unsigned short h16[4];
#pragma unroll
      for (int q = 0; q < 4; ++q) {
        const unsigned gru = (q & 2) ? giR.y : giR.x;
        const unsigned gzu = (q & 2) ? giZ.y : giZ.x;
        const unsigned gnu = (q & 2) ? giN.y : giN.x;
        float gr = h2f_(gru, q & 1);
        float gz = h2f_(gzu, q & 1);
        float gn = h2f_(gnu, q & 1);
        float r = __builtin_amdgcn_rcpf(1.f + __expf(-(gr + aR[q])));
        float z = __builtin_amdgcn_rcpf(1.f + __expf(-(gz + aZ[q])));
        float x = gn + r * aN[q];
        float e = __expf(-2.f * x);
        float n = 2.f * __builtin_amdgcn_rcpf(1.f + e) - 1.f;  // tanh
        float hnew = (1.f - z) * n + z * hq[s * 4 + q];
        hq[s * 4 + q] = hnew;
        hmax[s * 4 + q] = fmaxf(hmax[s * 4 + q], hnew);
        _Float16 hv = (_Float16)hnew;
        h16[q] = __builtin_bit_cast(unsigned short, hv);
      }
      uint2 hw;
      hw.x = (unsigned)h16[0] | ((unsigned)h16[1] << 16);
      hw.y = (unsigned)h16[2] | ((unsigned)h16[3] << 16);
      *(uint2*)&hT[(st + 1) & 1][nb][c0] = hw;
    }
    __syncthreads();
  }

  // Output: out[b][dir*256 + c], b = bg*16 + nb.
#pragma unroll
  for (int s = 0; s < 4; ++s) {
    const int c0 = (4 * w + s) * 16 + (lg << 2);
    float4 o = {hmax[s * 4 + 0], hmax[s * 4 + 1],
                hmax[s * 4 + 2], hmax[s * 4 + 3]};
    *(float4*)&out[(size_t)(bg * 16 + nb) * (2 * NH) + dir * NH + c0] = o;
  }
}

// ---------------------------------------------------------------------------
extern "C" void kernel_launch(void* const* d_in, const int* in_sizes, int n_in,
                              void* d_out, int out_size, void* d_ws, size_t ws_size,
                              hipStream_t stream) {
  const int*   tokens = (const int*)d_in[0];
  const float* emb    = (const float*)d_in[1];
  const float* Wc     = (const float*)d_in[2];
  const float* bc     = (const float*)d_in[3];
  const float* Wih_f  = (const float*)d_in[4];
  const float* Whh_f  = (const float*)d_in[5];
  const float* bih_f  = (const float*)d_in[6];
  const float* bhh_f  = (const float*)d_in[7];
  const float* Wih_b  = (const float*)d_in[8];
  const float* Whh_b  = (const float*)d_in[9];
  const float* bih_b  = (const float*)d_in[10];
  const float* bhh_b  = (const float*)d_in[11];
  float* out = (float*)d_out;

  // Workspace (f32 units): P[50000*128] | enc[4096*128] | GIp (6.29M f16)
  //                        | Apk (49152 uint4)
  float* P   = (float*)d_ws;
  float* enc = P + (size_t)NV * NC;
  unsigned short* GIp = (unsigned short*)(enc + (size_t)NB * NL * NC);
  uint4* Apk = (uint4*)(GIp + (size_t)2 * 2 * 128 * 3 * 16 * 256);

  // 0) Pack Whh -> MFMA A-fragments.
  conv_w_pack<<<dim3(192), dim3(256), 0, stream>>>(Whh_f, Whh_b, Apk);
  // 1) P = emb @ Wc^T   (V x C)
  gemm_bt_k128<<<dim3((NV + 63) / 64, NC / 128), dim3(256), 0, stream>>>(
      emb, Wc, nullptr, P, NV, NC);
  // 2) tree encode -> enc (B*L x C)
  tree_encode<<<dim3(NB * NL), dim3(128), 0, stream>>>(tokens, P, bc, enc);
  // 3) GI f+b, f16 scan layout, bhh_r/z folded.
  gemm_gi<<<dim3(NB * NL / 64, G3 / 128, 2), dim3(256), 0, stream>>>(
      enc, Wih_f, Wih_b, bih_f, bih_b, bhh_f, bhh_b, GIp, NB * NL, G3);
  // 4) GRU scan v11 — pinned W + MFMA (av-class residency).
  gru_scan_v11<<<dim3(4), dim3(256), 0, stream>>>(
      Apk, GIp, bhh_f, bhh_b, out);
}

// Round 12
// 461.803 us; speedup vs baseline: 1.4963x; 1.1057x over previous
//
#include <hip/hip_runtime.h>
#include <hip/hip_bf16.h>
#include <hip/hip_fp16.h>
#include <math.h>

// Problem constants: B=32, L=128, D=6, T=63, V=50000, E=C=128, H=256
#define NV 50000
#define NC 128
#define NH 256
#define NB 32
#define NL 128
#define NT 63
#define G3 768   // 3*H

typedef _Float16 f16x8 __attribute__((ext_vector_type(8)));
typedef _Float16 f16x2 __attribute__((ext_vector_type(2)));
typedef float f32x4 __attribute__((ext_vector_type(4)));

__device__ __forceinline__ float h2f_(unsigned int u, int hi) {
  f16x2 p = __builtin_bit_cast(f16x2, u);
  return (float)p[hi];
}

// ---------------------------------------------------------------------------
// C[m][n] = sum_k A[m][k]*B[n][k] (+bias), K=128, f32 out (for P = emb@Wc^T).
// ---------------------------------------------------------------------------
__global__ __launch_bounds__(256) void gemm_bt_k128(
    const float* __restrict__ A, const float* __restrict__ Bm,
    const float* __restrict__ bias, float* __restrict__ Cm,
    int M, int N) {
  __shared__ __align__(16) float As[64 * 129];
  __shared__ __align__(16) float BsT[64 * 132];  // [kk][n], one k-half
  const int m0 = blockIdx.x * 64;
  const int n0 = blockIdx.y * 128;
  const int tid = threadIdx.x;

#pragma unroll
  for (int i = 0; i < 32; ++i) {
    int e = tid + i * 256;
    int r = e >> 7, k = e & 127;
    int m = m0 + r;
    As[r * 129 + k] = (m < M) ? A[(size_t)m * 128 + k] : 0.0f;
  }

  const int tn = tid & 15;
  const int tm = tid >> 4;
  const int ml = tm * 4, nl = tn * 8;

  float acc[4][8];
#pragma unroll
  for (int i = 0; i < 4; ++i)
#pragma unroll
    for (int j = 0; j < 8; ++j) acc[i][j] = 0.0f;

#pragma unroll
  for (int h = 0; h < 2; ++h) {
    if (h) __syncthreads();
#pragma unroll
    for (int i = 0; i < 32; ++i) {
      int e = tid + i * 256;
      int n = e >> 6, kk = e & 63;
      BsT[kk * 132 + n] = Bm[(size_t)(n0 + n) * 128 + h * 64 + kk];
    }
    __syncthreads();
#pragma unroll 4
    for (int kk = 0; kk < 64; ++kk) {
      const int k = h * 64 + kk;
      float a0 = As[(ml + 0) * 129 + k];
      float a1 = As[(ml + 1) * 129 + k];
      float a2 = As[(ml + 2) * 129 + k];
      float a3 = As[(ml + 3) * 129 + k];
      float4 b0 = *(const float4*)&BsT[kk * 132 + nl];
      float4 b1 = *(const float4*)&BsT[kk * 132 + nl + 4];
      const float bv[8] = {b0.x, b0.y, b0.z, b0.w, b1.x, b1.y, b1.z, b1.w};
#pragma unroll
      for (int j = 0; j < 8; ++j) {
        acc[0][j] = fmaf(a0, bv[j], acc[0][j]);
        acc[1][j] = fmaf(a1, bv[j], acc[1][j]);
        acc[2][j] = fmaf(a2, bv[j], acc[2][j]);
        acc[3][j] = fmaf(a3, bv[j], acc[3][j]);
      }
    }
  }

  float bv[8];
#pragma unroll
  for (int j = 0; j < 8; ++j) bv[j] = bias ? bias[n0 + nl + j] : 0.0f;

#pragma unroll
  for (int i = 0; i < 4; ++i) {
    int m = m0 + ml + i;
    if (m < M) {
      float* crow = &Cm[(size_t)m * N + n0 + nl];
#pragma unroll
      for (int j = 0; j < 8; ++j) crow[j] = acc[i][j] + bv[j];
    }
  }
}

// ---------------------------------------------------------------------------
// GI GEMM: A = enc [4096][128], B = Wih_{f,b} [768][128] (z = dir).
// bias = bih + bhh for the r,z gates (n<512). Output in the scan's f16
// gate-lane layout: GIp[((dir*2+bg)*128 + t)*12288 + (rs*16 + nb)*256 + c]
// ---------------------------------------------------------------------------
__global__ __launch_bounds__(256) void gemm_gi(
    const float* __restrict__ A,
    const float* __restrict__ B0, const float* __restrict__ B1,
    const float* __restrict__ bias0, const float* __restrict__ bias1,
    const float* __restrict__ bh0, const float* __restrict__ bh1,
    unsigned short* __restrict__ GIp, int M, int N) {
  const float* __restrict__ Bm = blockIdx.z ? B1 : B0;
  const float* __restrict__ bias = blockIdx.z ? bias1 : bias0;
  const float* __restrict__ bh = blockIdx.z ? bh1 : bh0;

  __shared__ __align__(16) float As[64 * 129];
  __shared__ __align__(16) float BsT[64 * 132];
  const int m0 = blockIdx.x * 64;
  const int n0 = blockIdx.y * 128;
  const int tid = threadIdx.x;

#pragma unroll
  for (int i = 0; i < 32; ++i) {
    int e = tid + i * 256;
    int r = e >> 7, k = e & 127;
    int m = m0 + r;
    As[r * 129 + k] = (m < M) ? A[(size_t)m * 128 + k] : 0.0f;
  }

  const int tn = tid & 15;
  const int tm = tid >> 4;
  const int ml = tm * 4, nl = tn * 8;

  float acc[4][8];
#pragma unroll
  for (int i = 0; i < 4; ++i)
#pragma unroll
    for (int j = 0; j < 8; ++j) acc[i][j] = 0.0f;

#pragma unroll
  for (int h = 0; h < 2; ++h) {
    if (h) __syncthreads();
#pragma unroll
    for (int i = 0; i < 32; ++i) {
      int e = tid + i * 256;
      int n = e >> 6, kk = e & 63;
      BsT[kk * 132 + n] = Bm[(size_t)(n0 + n) * 128 + h * 64 + kk];
    }
    __syncthreads();
#pragma unroll 4
    for (int kk = 0; kk < 64; ++kk) {
      const int k = h * 64 + kk;
      float a0 = As[(ml + 0) * 129 + k];
      float a1 = As[(ml + 1) * 129 + k];
      float a2 = As[(ml + 2) * 129 + k];
      float a3 = As[(ml + 3) * 129 + k];
      float4 b0 = *(const float4*)&BsT[kk * 132 + nl];
      float4 b1 = *(const float4*)&BsT[kk * 132 + nl + 4];
      const float bv[8] = {b0.x, b0.y, b0.z, b0.w, b1.x, b1.y, b1.z, b1.w};
#pragma unroll
      for (int j = 0; j < 8; ++j) {
        acc[0][j] = fmaf(a0, bv[j], acc[0][j]);
        acc[1][j] = fmaf(a1, bv[j], acc[1][j]);
        acc[2][j] = fmaf(a2, bv[j], acc[2][j]);
        acc[3][j] = fmaf(a3, bv[j], acc[3][j]);
      }
    }
  }

  float bv[8];
#pragma unroll
  for (int j = 0; j < 8; ++j) {
    const int n = n0 + nl + j;
    bv[j] = bias[n] + (n < 512 ? bh[n] : 0.0f);  // fold bhh_r, bhh_z
  }

  const int ncol = n0 + nl;
  const int rs = ncol >> 8;
  const int cc = ncol & 255;
#pragma unroll
  for (int i = 0; i < 4; ++i) {
    int m = m0 + ml + i;
    if (m < M) {
      int b = m >> 7, t = m & 127;
      int bg = b >> 4, nb = b & 15;
      unsigned short hs[8];
#pragma unroll
      for (int j = 0; j < 8; ++j) {
        _Float16 hv = (_Float16)(acc[i][j] + bv[j]);
        hs[j] = __builtin_bit_cast(unsigned short, hv);
      }
      uint4 ov;
      ov.x = (unsigned)hs[0] | ((unsigned)hs[1] << 16);
      ov.y = (unsigned)hs[2] | ((unsigned)hs[3] << 16);
      ov.z = (unsigned)hs[4] | ((unsigned)hs[5] << 16);
      ov.w = (unsigned)hs[6] | ((unsigned)hs[7] << 16);
      size_t didx =
          ((((size_t)(blockIdx.z * 2 + bg) * 128 + t) * 3 + rs) * 16 + nb) * 256 + cc;
      *(uint4*)&GIp[didx] = ov;
    }
  }
}

// ---------------------------------------------------------------------------
// Tree encode: per (b,l), heap-sum P[tok], + cnt*bc, max, relu.
// ---------------------------------------------------------------------------
__global__ __launch_bounds__(128) void tree_encode(
    const int* __restrict__ tokens, const float* __restrict__ P,
    const float* __restrict__ bc, float* __restrict__ enc) {
  __shared__ int toks[NT];
  const int blk = blockIdx.x;
  const int c = threadIdx.x;
  if (c < NT) toks[c] = tokens[(size_t)blk * NT + c];
  __syncthreads();

  float s[NT];
#pragma unroll
  for (int i = 0; i < NT; ++i) s[i] = P[(size_t)toks[i] * NC + c];
#pragma unroll
  for (int i = 30; i >= 0; --i) s[i] += s[2 * i + 1] + s[2 * i + 2];

  const float bcv = bc[c];
  float m = -1e30f;
#pragma unroll
  for (int i = 0; i < NT; ++i) {
    const float cnt = (i == 0) ? 63.0f
                    : (i < 3)  ? 31.0f
                    : (i < 7)  ? 15.0f
                    : (i < 15) ? 7.0f
                    : (i < 31) ? 3.0f
                               : 1.0f;
    m = fmaxf(m, s[i] + cnt * bcv);
  }
  enc[(size_t)blk * NC + c] = fmaxf(m, 0.0f);
}

// ---------------------------------------------------------------------------
// Pack Whh f32 [768][256] -> MFMA A-fragments (f16), LAYOUT VERIFIED in R8:
//   Apk[(((dir*16 + cs)*3 + mt)*8 + ks)*64 + lane]:
//     Wrow = 16*cs + 256*mt + (lane&15),  k(j) = ks*32 + (lane>>4)*8 + j
// ---------------------------------------------------------------------------
__global__ __launch_bounds__(256) void conv_w_pack(
    const float* __restrict__ Wf, const float* __restrict__ Wb,
    uint4* __restrict__ Apk) {
  int i = blockIdx.x * 256 + threadIdx.x;  // [0, 2*16*3*8*64)
  if (i >= 2 * 16 * 3 * 8 * 64) return;
  const int dir = i / 24576;
  int rem = i - dir * 24576;
  const int cs = rem / 1536; rem -= cs * 1536;
  const int mt = rem / 512; rem -= mt * 512;
  const int ks = rem >> 6;
  const int lane = rem & 63;
  const int Wrow = 16 * cs + 256 * mt + (lane & 15);
  const int k0 = ks * 32 + ((lane >> 4) << 3);
  const float* __restrict__ W = dir ? Wb : Wf;
  const float4 a = *(const float4*)&W[(size_t)Wrow * NH + k0];
  const float4 b = *(const float4*)&W[(size_t)Wrow * NH + k0 + 4];
  const float v[8] = {a.x, a.y, a.z, a.w, b.x, b.y, b.z, b.w};
  unsigned short hs[8];
#pragma unroll
  for (int j = 0; j < 8; ++j) {
    _Float16 hv = (_Float16)v[j];
    hs[j] = __builtin_bit_cast(unsigned short, hv);
  }
  uint4 o;
  o.x = (unsigned)hs[0] | ((unsigned)hs[1] << 16);
  o.y = (unsigned)hs[2] | ((unsigned)hs[3] << 16);
  o.z = (unsigned)hs[4] | ((unsigned)hs[5] << 16);
  o.w = (unsigned)hs[6] | ((unsigned)hs[7] << 16);
  Apk[i] = o;
}

// ---------------------------------------------------------------------------
// GRU scan v12 — W forced into AGPRs via explicit v_accvgpr_write (scalar,
// NON-TIED "=a" outputs: avoids R9's tied-128-bit compile error, and unlike
// v11's "+v" pins does NOT confine W to the 256-cap arch-VGPR file).
// 4 blocks (dir x bg16) x 512 threads (8 waves, 2/SIMD, 256 unified
// regs/thread). Wave w owns channel-sets {2w, 2w+1}: W = 48 uint4 =
// 192 AGPR dwords/thread; VGPR working set hand-trimmed (~60): channel-sets
// processed sequentially, B-fragments 2-deep pipelined from LDS.
// MFMA A-operands are av-class -> read straight from AGPRs, zero per-use
// copies. One barrier/step.
// ---------------------------------------------------------------------------
__global__ __launch_bounds__(512, 2) void gru_scan_v12(
    const uint4* __restrict__ Apk, const unsigned short* __restrict__ GIp,
    const float* __restrict__ bhh_f, const float* __restrict__ bhh_b,
    float* __restrict__ out) {
  const int dir = blockIdx.x >> 1;
  const int bg = blockIdx.x & 1;
  const int tid = threadIdx.x;
  const int w = tid >> 6;      // wave [0,8)
  const int lane = tid & 63;
  const int lg = lane >> 4;    // k-group / D-row group
  const int nb = lane & 15;    // batch col within group

  __shared__ __align__(16) unsigned short hT[2][16][264];

  // One-time W fill: coalesced loads -> explicit AGPR writes. The asm
  // volatile "=a" defs are unmovable/unremovable and live in the AGPR half.
  uint4 wa[48];
#pragma unroll
  for (int q = 0; q < 48; ++q) {
    const int s = q / 24, mt = (q / 8) % 3, ks = q & 7;
    uint4 t =
        Apk[((((size_t)dir * 16 + (2 * w + s)) * 3 + mt) * 8 + ks) * 64 + lane];
    asm volatile("v_accvgpr_write_b32 %0, %1" : "=a"(wa[q].x) : "v"(t.x));
    asm volatile("v_accvgpr_write_b32 %0, %1" : "=a"(wa[q].y) : "v"(t.y));
    asm volatile("v_accvgpr_write_b32 %0, %1" : "=a"(wa[q].z) : "v"(t.z));
    asm volatile("v_accvgpr_write_b32 %0, %1" : "=a"(wa[q].w) : "v"(t.w));
  }

  const float* __restrict__ bhh = dir ? bhh_b : bhh_f;
  // bhh_n for this lane's 8 channels (2 sets x 4), packed f16 (4 dwords).
  uint2 bn16[2];
#pragma unroll
  for (int s = 0; s < 2; ++s) {
    const int c0 = (2 * w + s) * 16 + (lg << 2);
    float4 b4 = *(const float4*)&bhh[2 * NH + c0];
    _Float16 h0 = (_Float16)b4.x, h1 = (_Float16)b4.y;
    _Float16 h2 = (_Float16)b4.z, h3 = (_Float16)b4.w;
    bn16[s].x = (unsigned)__builtin_bit_cast(unsigned short, h0) |
                ((unsigned)__builtin_bit_cast(unsigned short, h1) << 16);
    bn16[s].y = (unsigned)__builtin_bit_cast(unsigned short, h2) |
                ((unsigned)__builtin_bit_cast(unsigned short, h3) << 16);
  }

  // Zero h buffer 0 (2112 uints).
  for (int i = tid; i < 16 * 264 / 2; i += 512) ((unsigned int*)hT)[i] = 0u;

  const unsigned short* __restrict__ gi_blk =
      GIp + (size_t)((dir * 2 + bg) * 128) * 12288;

  float hq[8], hmax[8];
#pragma unroll
  for (int q = 0; q < 8; ++q) { hq[q] = 0.0f; hmax[q] = -1e30f; }
  __syncthreads();

  for (int st = 0; st < NL; ++st) {
    const int t = dir ? (NL - 1 - st) : st;
    const unsigned short* __restrict__ git = gi_blk + (size_t)t * 12288;
    const unsigned short* __restrict__ hrow = &hT[st & 1][nb][lg << 3];

#pragma unroll
    for (int s = 0; s < 2; ++s) {
      const int c0 = (2 * w + s) * 16 + (lg << 2);
      // gi loads issue first; latency hides under the 24-MFMA chain.
      uint2 giR = *(const uint2*)(git + (0 * 16 + nb) * 256 + c0);
      uint2 giZ = *(const uint2*)(git + (1 * 16 + nb) * 256 + c0);
      uint2 giN = *(const uint2*)(git + (2 * 16 + nb) * 256 + c0);

      f32x4 aR = {0.f, 0.f, 0.f, 0.f};
      f32x4 aZ = {0.f, 0.f, 0.f, 0.f};
      f32x4 aN = {h2f_(bn16[s].x, 0), h2f_(bn16[s].x, 1),
                  h2f_(bn16[s].y, 0), h2f_(bn16[s].y, 1)};  // + bhh_n

      // 2-deep pipelined B-fragments (only 2 uint4 live -> low VGPR peak).
      uint4 bcur = *(const uint4*)(hrow);
#pragma unroll
      for (int ks = 0; ks < 8; ++ks) {
        uint4 bnxt = bcur;
        if (ks < 7) bnxt = *(const uint4*)(hrow + (ks + 1) * 32);
        f16x8 bv = __builtin_bit_cast(f16x8, bcur);
        aR = __builtin_amdgcn_mfma_f32_16x16x32_f16(
            __builtin_bit_cast(f16x8, wa[s * 24 + 0 + ks]), bv, aR, 0, 0, 0);
        aZ = __builtin_amdgcn_mfma_f32_16x16x32_f16(
            __builtin_bit_cast(f16x8, wa[s * 24 + 8 + ks]), bv, aZ, 0, 0, 0);
        aN = __builtin_amdgcn_mfma_f32_16x16x32_f16(
            __builtin_bit_cast(f16x8, wa[s * 24 + 16 + ks]), bv, aN, 0, 0, 0);
        bcur = bnxt;
      }

      unsigned short h16[4];
#pragma unroll
      for (int q = 0; q < 4; ++q) {
        const unsigned gru = (q & 2) ? giR.y : giR.x;
        const unsigned gzu = (q & 2) ? giZ.y : giZ.x;
        const unsigned gnu = (q & 2) ? giN.y : giN.x;
        float gr = h2f_(gru, q & 1);
        float gz = h2f_(gzu, q & 1);
        float gn = h2f_(gnu, q & 1);
        float r = __builtin_amdgcn_rcpf(1.f + __expf(-(gr + aR[q])));
        float z = __builtin_amdgcn_rcpf(1.f + __expf(-(gz + aZ[q])));
        float x = gn + r * aN[q];
        float e = __expf(-2.f * x);
        float n = 2.f * __builtin_amdgcn_rcpf(1.f + e) - 1.f;  // tanh
        float hnew = (1.f - z) * n + z * hq[s * 4 + q];
        hq[s * 4 + q] = hnew;
        hmax[s * 4 + q] = fmaxf(hmax[s * 4 + q], hnew);
        _Float16 hv = (_Float16)hnew;
        h16[q] = __builtin_bit_cast(unsigned short, hv);
      }
      uint2 hw;
      hw.x = (unsigned)h16[0] | ((unsigned)h16[1] << 16);
      hw.y = (unsigned)h16[2] | ((unsigned)h16[3] << 16);
      *(uint2*)&hT[(st + 1) & 1][nb][c0] = hw;
    }
    __syncthreads();
  }

  // Output: out[b][dir*256 + c], b = bg*16 + nb.
#pragma unroll
  for (int s = 0; s < 2; ++s) {
    const int c0 = (2 * w + s) * 16 + (lg << 2);
    float4 o = {hmax[s * 4 + 0], hmax[s * 4 + 1],
                hmax[s * 4 + 2], hmax[s * 4 + 3]};
    *(float4*)&out[(size_t)(bg * 16 + nb) * (2 * NH) + dir * NH + c0] = o;
  }
}

// ---------------------------------------------------------------------------
extern "C" void kernel_launch(void* const* d_in, const int* in_sizes, int n_in,
                              void* d_out, int out_size, void* d_ws, size_t ws_size,
                              hipStream_t stream) {
  const int*   tokens = (const int*)d_in[0];
  const float* emb    = (const float*)d_in[1];
  const float* Wc     = (const float*)d_in[2];
  const float* bc     = (const float*)d_in[3];
  const float* Wih_f  = (const float*)d_in[4];
  const float* Whh_f  = (const float*)d_in[5];
  const float* bih_f  = (const float*)d_in[6];
  const float* bhh_f  = (const float*)d_in[7];
  const float* Wih_b  = (const float*)d_in[8];
  const float* Whh_b  = (const float*)d_in[9];
  const float* bih_b  = (const float*)d_in[10];
  const float* bhh_b  = (const float*)d_in[11];
  float* out = (float*)d_out;

  // Workspace (f32 units): P[50000*128] | enc[4096*128] | GIp (6.29M f16)
  //                        | Apk (49152 uint4)
  float* P   = (float*)d_ws;
  float* enc = P + (size_t)NV * NC;
  unsigned short* GIp = (unsigned short*)(enc + (size_t)NB * NL * NC);
  uint4* Apk = (uint4*)(GIp + (size_t)2 * 2 * 128 * 3 * 16 * 256);

  // 0) Pack Whh -> MFMA A-fragments.
  conv_w_pack<<<dim3(192), dim3(256), 0, stream>>>(Whh_f, Whh_b, Apk);
  // 1) P = emb @ Wc^T   (V x C)
  gemm_bt_k128<<<dim3((NV + 63) / 64, NC / 128), dim3(256), 0, stream>>>(
      emb, Wc, nullptr, P, NV, NC);
  // 2) tree encode -> enc (B*L x C)
  tree_encode<<<dim3(NB * NL), dim3(128), 0, stream>>>(tokens, P, bc, enc);
  // 3) GI f+b, f16 scan layout, bhh_r/z folded.
  gemm_gi<<<dim3(NB * NL / 64, G3 / 128, 2), dim3(256), 0, stream>>>(
      enc, Wih_f, Wih_b, bih_f, bih_b, bhh_f, bhh_b, GIp, NB * NL, G3);
  // 4) GRU scan v12 — W in AGPRs via explicit v_accvgpr_write.
  gru_scan_v12<<<dim3(4), dim3(512), 0, stream>>>(
      Apk, GIp, bhh_f, bhh_b, out);
}

// Round 13
// 419.317 us; speedup vs baseline: 1.6480x; 1.1013x over previous
//
#include <hip/hip_runtime.h>
#include <hip/hip_bf16.h>
#include <hip/hip_fp16.h>
#include <math.h>

// Problem constants: B=32, L=128, D=6, T=63, V=50000, E=C=128, H=256
#define NV 50000
#define NC 128
#define NH 256
#define NB 32
#define NL 128
#define NT 63
#define G3 768   // 3*H

typedef _Float16 f16x8 __attribute__((ext_vector_type(8)));
typedef _Float16 f16x2 __attribute__((ext_vector_type(2)));
typedef float f32x4 __attribute__((ext_vector_type(4)));

__device__ __forceinline__ float h2f_(unsigned int u, int hi) {
  f16x2 p = __builtin_bit_cast(f16x2, u);
  return (float)p[hi];
}

// ---------------------------------------------------------------------------
// C[m][n] = sum_k A[m][k]*B[n][k] (+bias), K=128, f32 out (for P = emb@Wc^T).
// ---------------------------------------------------------------------------
__global__ __launch_bounds__(256) void gemm_bt_k128(
    const float* __restrict__ A, const float* __restrict__ Bm,
    const float* __restrict__ bias, float* __restrict__ Cm,
    int M, int N) {
  __shared__ __align__(16) float As[64 * 129];
  __shared__ __align__(16) float BsT[64 * 132];  // [kk][n], one k-half
  const int m0 = blockIdx.x * 64;
  const int n0 = blockIdx.y * 128;
  const int tid = threadIdx.x;

#pragma unroll
  for (int i = 0; i < 32; ++i) {
    int e = tid + i * 256;
    int r = e >> 7, k = e & 127;
    int m = m0 + r;
    As[r * 129 + k] = (m < M) ? A[(size_t)m * 128 + k] : 0.0f;
  }

  const int tn = tid & 15;
  const int tm = tid >> 4;
  const int ml = tm * 4, nl = tn * 8;

  float acc[4][8];
#pragma unroll
  for (int i = 0; i < 4; ++i)
#pragma unroll
    for (int j = 0; j < 8; ++j) acc[i][j] = 0.0f;

#pragma unroll
  for (int h = 0; h < 2; ++h) {
    if (h) __syncthreads();
#pragma unroll
    for (int i = 0; i < 32; ++i) {
      int e = tid + i * 256;
      int n = e >> 6, kk = e & 63;
      BsT[kk * 132 + n] = Bm[(size_t)(n0 + n) * 128 + h * 64 + kk];
    }
    __syncthreads();
#pragma unroll 4
    for (int kk = 0; kk < 64; ++kk) {
      const int k = h * 64 + kk;
      float a0 = As[(ml + 0) * 129 + k];
      float a1 = As[(ml + 1) * 129 + k];
      float a2 = As[(ml + 2) * 129 + k];
      float a3 = As[(ml + 3) * 129 + k];
      float4 b0 = *(const float4*)&BsT[kk * 132 + nl];
      float4 b1 = *(const float4*)&BsT[kk * 132 + nl + 4];
      const float bv[8] = {b0.x, b0.y, b0.z, b0.w, b1.x, b1.y, b1.z, b1.w};
#pragma unroll
      for (int j = 0; j < 8; ++j) {
        acc[0][j] = fmaf(a0, bv[j], acc[0][j]);
        acc[1][j] = fmaf(a1, bv[j], acc[1][j]);
        acc[2][j] = fmaf(a2, bv[j], acc[2][j]);
        acc[3][j] = fmaf(a3, bv[j], acc[3][j]);
      }
    }
  }

  float bv[8];
#pragma unroll
  for (int j = 0; j < 8; ++j) bv[j] = bias ? bias[n0 + nl + j] : 0.0f;

#pragma unroll
  for (int i = 0; i < 4; ++i) {
    int m = m0 + ml + i;
    if (m < M) {
      float* crow = &Cm[(size_t)m * N + n0 + nl];
#pragma unroll
      for (int j = 0; j < 8; ++j) crow[j] = acc[i][j] + bv[j];
    }
  }
}

// ---------------------------------------------------------------------------
// GI GEMM: A = enc [4096][128], B = Wih_{f,b} [768][128] (z = dir).
// bias = bih + bhh for the r,z gates (n<512). Output in the scan's f16
// gate-lane layout: GIp[((dir*2+bg)*128 + t)*12288 + (rs*16 + nb)*256 + c]
// ---------------------------------------------------------------------------
__global__ __launch_bounds__(256) void gemm_gi(
    const float* __restrict__ A,
    const float* __restrict__ B0, const float* __restrict__ B1,
    const float* __restrict__ bias0, const float* __restrict__ bias1,
    const float* __restrict__ bh0, const float* __restrict__ bh1,
    unsigned short* __restrict__ GIp, int M, int N) {
  const float* __restrict__ Bm = blockIdx.z ? B1 : B0;
  const float* __restrict__ bias = blockIdx.z ? bias1 : bias0;
  const float* __restrict__ bh = blockIdx.z ? bh1 : bh0;

  __shared__ __align__(16) float As[64 * 129];
  __shared__ __align__(16) float BsT[64 * 132];
  const int m0 = blockIdx.x * 64;
  const int n0 = blockIdx.y * 128;
  const int tid = threadIdx.x;

#pragma unroll
  for (int i = 0; i < 32; ++i) {
    int e = tid + i * 256;
    int r = e >> 7, k = e & 127;
    int m = m0 + r;
    As[r * 129 + k] = (m < M) ? A[(size_t)m * 128 + k] : 0.0f;
  }

  const int tn = tid & 15;
  const int tm = tid >> 4;
  const int ml = tm * 4, nl = tn * 8;

  float acc[4][8];
#pragma unroll
  for (int i = 0; i < 4; ++i)
#pragma unroll
    for (int j = 0; j < 8; ++j) acc[i][j] = 0.0f;

#pragma unroll
  for (int h = 0; h < 2; ++h) {
    if (h) __syncthreads();
#pragma unroll
    for (int i = 0; i < 32; ++i) {
      int e = tid + i * 256;
      int n = e >> 6, kk = e & 63;
      BsT[kk * 132 + n] = Bm[(size_t)(n0 + n) * 128 + h * 64 + kk];
    }
    __syncthreads();
#pragma unroll 4
    for (int kk = 0; kk < 64; ++kk) {
      const int k = h * 64 + kk;
      float a0 = As[(ml + 0) * 129 + k];
      float a1 = As[(ml + 1) * 129 + k];
      float a2 = As[(ml + 2) * 129 + k];
      float a3 = As[(ml + 3) * 129 + k];
      float4 b0 = *(const float4*)&BsT[kk * 132 + nl];
      float4 b1 = *(const float4*)&BsT[kk * 132 + nl + 4];
      const float bv[8] = {b0.x, b0.y, b0.z, b0.w, b1.x, b1.y, b1.z, b1.w};
#pragma unroll
      for (int j = 0; j < 8; ++j) {
        acc[0][j] = fmaf(a0, bv[j], acc[0][j]);
        acc[1][j] = fmaf(a1, bv[j], acc[1][j]);
        acc[2][j] = fmaf(a2, bv[j], acc[2][j]);
        acc[3][j] = fmaf(a3, bv[j], acc[3][j]);
      }
    }
  }

  float bv[8];
#pragma unroll
  for (int j = 0; j < 8; ++j) {
    const int n = n0 + nl + j;
    bv[j] = bias[n] + (n < 512 ? bh[n] : 0.0f);  // fold bhh_r, bhh_z
  }

  const int ncol = n0 + nl;
  const int rs = ncol >> 8;
  const int cc = ncol & 255;
#pragma unroll
  for (int i = 0; i < 4; ++i) {
    int m = m0 + ml + i;
    if (m < M) {
      int b = m >> 7, t = m & 127;
      int bg = b >> 4, nb = b & 15;
      unsigned short hs[8];
#pragma unroll
      for (int j = 0; j < 8; ++j) {
        _Float16 hv = (_Float16)(acc[i][j] + bv[j]);
        hs[j] = __builtin_bit_cast(unsigned short, hv);
      }
      uint4 ov;
      ov.x = (unsigned)hs[0] | ((unsigned)hs[1] << 16);
      ov.y = (unsigned)hs[2] | ((unsigned)hs[3] << 16);
      ov.z = (unsigned)hs[4] | ((unsigned)hs[5] << 16);
      ov.w = (unsigned)hs[6] | ((unsigned)hs[7] << 16);
      size_t didx =
          ((((size_t)(blockIdx.z * 2 + bg) * 128 + t) * 3 + rs) * 16 + nb) * 256 + cc;
      *(uint4*)&GIp[didx] = ov;
    }
  }
}

// ---------------------------------------------------------------------------
// Tree encode: per (b,l), heap-sum P[tok], + cnt*bc, max, relu.
// ---------------------------------------------------------------------------
__global__ __launch_bounds__(128) void tree_encode(
    const int* __restrict__ tokens, const float* __restrict__ P,
    const float* __restrict__ bc, float* __restrict__ enc) {
  __shared__ int toks[NT];
  const int blk = blockIdx.x;
  const int c = threadIdx.x;
  if (c < NT) toks[c] = tokens[(size_t)blk * NT + c];
  __syncthreads();

  float s[NT];
#pragma unroll
  for (int i = 0; i < NT; ++i) s[i] = P[(size_t)toks[i] * NC + c];
#pragma unroll
  for (int i = 30; i >= 0; --i) s[i] += s[2 * i + 1] + s[2 * i + 2];

  const float bcv = bc[c];
  float m = -1e30f;
#pragma unroll
  for (int i = 0; i < NT; ++i) {
    const float cnt = (i == 0) ? 63.0f
                    : (i < 3)  ? 31.0f
                    : (i < 7)  ? 15.0f
                    : (i < 15) ? 7.0f
                    : (i < 31) ? 3.0f
                               : 1.0f;
    m = fmaxf(m, s[i] + cnt * bcv);
  }
  enc[(size_t)blk * NC + c] = fmaxf(m, 0.0f);
}

// ---------------------------------------------------------------------------
// Pack Whh f32 [768][256] -> MFMA A-fragments (f16), LAYOUT VERIFIED in R8:
//   Apk[(((dir*16 + cs)*3 + mt)*8 + ks)*64 + lane]:
//     Wrow = 16*cs + 256*mt + (lane&15),  k(j) = ks*32 + (lane>>4)*8 + j
// ---------------------------------------------------------------------------
__global__ __launch_bounds__(256) void conv_w_pack(
    const float* __restrict__ Wf, const float* __restrict__ Wb,
    uint4* __restrict__ Apk) {
  int i = blockIdx.x * 256 + threadIdx.x;  // [0, 2*16*3*8*64)
  if (i >= 2 * 16 * 3 * 8 * 64) return;
  const int dir = i / 24576;
  int rem = i - dir * 24576;
  const int cs = rem / 1536; rem -= cs * 1536;
  const int mt = rem / 512; rem -= mt * 512;
  const int ks = rem >> 6;
  const int lane = rem & 63;
  const int Wrow = 16 * cs + 256 * mt + (lane & 15);
  const int k0 = ks * 32 + ((lane >> 4) << 3);
  const float* __restrict__ W = dir ? Wb : Wf;
  const float4 a = *(const float4*)&W[(size_t)Wrow * NH + k0];
  const float4 b = *(const float4*)&W[(size_t)Wrow * NH + k0 + 4];
  const float v[8] = {a.x, a.y, a.z, a.w, b.x, b.y, b.z, b.w};
  unsigned short hs[8];
#pragma unroll
  for (int j = 0; j < 8; ++j) {
    _Float16 hv = (_Float16)v[j];
    hs[j] = __builtin_bit_cast(unsigned short, hv);
  }
  uint4 o;
  o.x = (unsigned)hs[0] | ((unsigned)hs[1] << 16);
  o.y = (unsigned)hs[2] | ((unsigned)hs[3] << 16);
  o.z = (unsigned)hs[4] | ((unsigned)hs[5] << 16);
  o.w = (unsigned)hs[6] | ((unsigned)hs[7] << 16);
  Apk[i] = o;
}

// ---------------------------------------------------------------------------
// GRU scan v13 — NO ARRAYS. Root cause of v3-v12: the W array was a
// variable-indexed alloca at SROA time -> scratch-resident (L2-cached, so
// WRITE_SIZE stayed small) -> re-read 393KB/step/CU = 6100cy. Fix: 48
// individually NAMED uint4 SSA values, literal-index loads, no alloca.
// 4 blocks (dir x bg16) x 512 threads (8 waves, 2/SIMD, 256 unified regs).
// Wave w owns channel-sets {2w,2w+1}: W = 192 dwords + lean working set
// (~58: 3-deep named B-frag rotation, packed-f16 h carry, v_pk_max_f16
// running max) = ~250 <= 256 -> allocator never needs to spill.
// ---------------------------------------------------------------------------
#define WLOAD(q)                                                              \
  Apk[((((size_t)dir * 16 + (2 * w + ((q) / 24))) * 3 + (((q) / 8) % 3)) * 8 + \
       ((q)&7)) * 64 + lane]
#define WDECL(n)                                                              \
  uint4 w##n = WLOAD(n);                                                      \
  asm volatile("" : "+v"(w##n.x), "+v"(w##n.y), "+v"(w##n.z), "+v"(w##n.w));
#define KS(B, WR, WZ, WN)                                                     \
  {                                                                           \
    f16x8 bv_ = __builtin_bit_cast(f16x8, B);                                 \
    aR = __builtin_amdgcn_mfma_f32_16x16x32_f16(                              \
        __builtin_bit_cast(f16x8, WR), bv_, aR, 0, 0, 0);                     \
    aZ = __builtin_amdgcn_mfma_f32_16x16x32_f16(                              \
        __builtin_bit_cast(f16x8, WZ), bv_, aZ, 0, 0, 0);                     \
    aN = __builtin_amdgcn_mfma_f32_16x16x32_f16(                              \
        __builtin_bit_cast(f16x8, WN), bv_, aN, 0, 0, 0);                     \
  }
#define PKMAX(D, S)                                                           \
  asm("v_pk_max_f16 %0, %1, %2" : "=v"(D) : "v"(D), "v"(S))

__global__ __launch_bounds__(512, 2) void gru_scan_v13(
    const uint4* __restrict__ Apk, const unsigned short* __restrict__ GIp,
    const float* __restrict__ bhh_f, const float* __restrict__ bhh_b,
    float* __restrict__ out) {
  const int dir = blockIdx.x >> 1;
  const int bg = blockIdx.x & 1;
  const int tid = threadIdx.x;
  const int w = tid >> 6;      // wave [0,8)
  const int lane = tid & 63;
  const int lg = lane >> 4;    // k-group / D-row group
  const int nb = lane & 15;    // batch col within group

  __shared__ __align__(16) unsigned short hT[2][16][264];

  // ---- One-time W fill: 48 NAMED SSA values (no alloca, no SROA trap). ----
  WDECL(0)  WDECL(1)  WDECL(2)  WDECL(3)  WDECL(4)  WDECL(5)  WDECL(6)  WDECL(7)
  WDECL(8)  WDECL(9)  WDECL(10) WDECL(11) WDECL(12) WDECL(13) WDECL(14) WDECL(15)
  WDECL(16) WDECL(17) WDECL(18) WDECL(19) WDECL(20) WDECL(21) WDECL(22) WDECL(23)
  WDECL(24) WDECL(25) WDECL(26) WDECL(27) WDECL(28) WDECL(29) WDECL(30) WDECL(31)
  WDECL(32) WDECL(33) WDECL(34) WDECL(35) WDECL(36) WDECL(37) WDECL(38) WDECL(39)
  WDECL(40) WDECL(41) WDECL(42) WDECL(43) WDECL(44) WDECL(45) WDECL(46) WDECL(47)

  const float* __restrict__ bhh = dir ? bhh_b : bhh_f;
  const int c00 = (2 * w) * 16 + (lg << 2);
  const int c01 = c00 + 16;
  // bhh_n packed f16 (2 dwords per set).
  uint2 bn0, bn1;
  {
    float4 b4 = *(const float4*)&bhh[2 * NH + c00];
    _Float16 h0 = (_Float16)b4.x, h1 = (_Float16)b4.y;
    _Float16 h2 = (_Float16)b4.z, h3 = (_Float16)b4.w;
    bn0.x = (unsigned)__builtin_bit_cast(unsigned short, h0) |
            ((unsigned)__builtin_bit_cast(unsigned short, h1) << 16);
    bn0.y = (unsigned)__builtin_bit_cast(unsigned short, h2) |
            ((unsigned)__builtin_bit_cast(unsigned short, h3) << 16);
    float4 c4 = *(const float4*)&bhh[2 * NH + c01];
    _Float16 g0 = (_Float16)c4.x, g1 = (_Float16)c4.y;
    _Float16 g2 = (_Float16)c4.z, g3 = (_Float16)c4.w;
    bn1.x = (unsigned)__builtin_bit_cast(unsigned short, g0) |
            ((unsigned)__builtin_bit_cast(unsigned short, g1) << 16);
    bn1.y = (unsigned)__builtin_bit_cast(unsigned short, g2) |
            ((unsigned)__builtin_bit_cast(unsigned short, g3) << 16);
  }

  // Zero h buffer 0.
  for (int i = tid; i < 16 * 264 / 2; i += 512) ((unsigned int*)hT)[i] = 0u;

  const unsigned short* __restrict__ gi_blk =
      GIp + (size_t)((dir * 2 + bg) * 128) * 12288;

  // h carry + running max, packed f16 (uint2 per set). -inf = 0xFC00.
  uint2 hc0 = {0u, 0u}, hc1 = {0u, 0u};
  uint2 hm0 = {0xFC00FC00u, 0xFC00FC00u}, hm1 = {0xFC00FC00u, 0xFC00FC00u};
  __syncthreads();

  for (int st = 0; st < NL; ++st) {
    const int t = dir ? (NL - 1 - st) : st;
    const unsigned short* __restrict__ git = gi_blk + (size_t)t * 12288;
    const unsigned short* __restrict__ hrow = &hT[st & 1][nb][lg << 3];

    // ---------------- SET 0 (channels c00..c00+3) ----------------
    {
      uint2 giR = *(const uint2*)(git + (0 * 16 + nb) * 256 + c00);
      uint2 giZ = *(const uint2*)(git + (1 * 16 + nb) * 256 + c00);
      uint2 giN = *(const uint2*)(git + (2 * 16 + nb) * 256 + c00);
      f32x4 aR = {0.f, 0.f, 0.f, 0.f};
      f32x4 aZ = {0.f, 0.f, 0.f, 0.f};
      f32x4 aN = {h2f_(bn0.x, 0), h2f_(bn0.x, 1), h2f_(bn0.y, 0),
                  h2f_(bn0.y, 1)};
      uint4 bA = *(const uint4*)(hrow + 0 * 32);
      uint4 bB = *(const uint4*)(hrow + 1 * 32);
      uint4 bC = *(const uint4*)(hrow + 2 * 32);
      KS(bA, w0, w8, w16);  bA = *(const uint4*)(hrow + 3 * 32);
      KS(bB, w1, w9, w17);  bB = *(const uint4*)(hrow + 4 * 32);
      KS(bC, w2, w10, w18); bC = *(const uint4*)(hrow + 5 * 32);
      KS(bA, w3, w11, w19); bA = *(const uint4*)(hrow + 6 * 32);
      KS(bB, w4, w12, w20); bB = *(const uint4*)(hrow + 7 * 32);
      KS(bC, w5, w13, w21);
      KS(bA, w6, w14, w22);
      KS(bB, w7, w15, w23);

      unsigned short h16[4];
#pragma unroll
      for (int q = 0; q < 4; ++q) {
        float gr = h2f_(q & 2 ? giR.y : giR.x, q & 1);
        float gz = h2f_(q & 2 ? giZ.y : giZ.x, q & 1);
        float gn = h2f_(q & 2 ? giN.y : giN.x, q & 1);
        float hp = h2f_(q & 2 ? hc0.y : hc0.x, q & 1);
        float r = __builtin_amdgcn_rcpf(1.f + __expf(-(gr + aR[q])));
        float z = __builtin_amdgcn_rcpf(1.f + __expf(-(gz + aZ[q])));
        float x = gn + r * aN[q];
        float e = __expf(-2.f * x);
        float n = 2.f * __builtin_amdgcn_rcpf(1.f + e) - 1.f;  // tanh
        float hnew = (1.f - z) * n + z * hp;
        _Float16 hv = (_Float16)hnew;
        h16[q] = __builtin_bit_cast(unsigned short, hv);
      }
      hc0.x = (unsigned)h16[0] | ((unsigned)h16[1] << 16);
      hc0.y = (unsigned)h16[2] | ((unsigned)h16[3] << 16);
      PKMAX(hm0.x, hc0.x);
      PKMAX(hm0.y, hc0.y);
      *(uint2*)&hT[(st + 1) & 1][nb][c00] = hc0;
    }

    // ---------------- SET 1 (channels c01..c01+3) ----------------
    {
      uint2 giR = *(const uint2*)(git + (0 * 16 + nb) * 256 + c01);
      uint2 giZ = *(const uint2*)(git + (1 * 16 + nb) * 256 + c01);
      uint2 giN = *(const uint2*)(git + (2 * 16 + nb) * 256 + c01);
      f32x4 aR = {0.f, 0.f, 0.f, 0.f};
      f32x4 aZ = {0.f, 0.f, 0.f, 0.f};
      f32x4 aN = {h2f_(bn1.x, 0), h2f_(bn1.x, 1), h2f_(bn1.y, 0),
                  h2f_(bn1.y, 1)};
      uint4 bA = *(const uint4*)(hrow + 0 * 32);
      uint4 bB = *(const uint4*)(hrow + 1 * 32);
      uint4 bC = *(const uint4*)(hrow + 2 * 32);
      KS(bA, w24, w32, w40); bA = *(const uint4*)(hrow + 3 * 32);
      KS(bB, w25, w33, w41); bB = *(const uint4*)(hrow + 4 * 32);
      KS(bC, w26, w34, w42); bC = *(const uint4*)(hrow + 5 * 32);
      KS(bA, w27, w35, w43); bA = *(const uint4*)(hrow + 6 * 32);
      KS(bB, w28, w36, w44); bB = *(const uint4*)(hrow + 7 * 32);
      KS(bC, w29, w37, w45);
      KS(bA, w30, w38, w46);
      KS(bB, w31, w39, w47);

      unsigned short h16[4];
#pragma unroll
      for (int q = 0; q < 4; ++q) {
        float gr = h2f_(q & 2 ? giR.y : giR.x, q & 1);
        float gz = h2f_(q & 2 ? giZ.y : giZ.x, q & 1);
        float gn = h2f_(q & 2 ? giN.y : giN.x, q & 1);
        float hp = h2f_(q & 2 ? hc1.y : hc1.x, q & 1);
        float r = __builtin_amdgcn_rcpf(1.f + __expf(-(gr + aR[q])));
        float z = __builtin_amdgcn_rcpf(1.f + __expf(-(gz + aZ[q])));
        float x = gn + r * aN[q];
        float e = __expf(-2.f * x);
        float n = 2.f * __builtin_amdgcn_rcpf(1.f + e) - 1.f;  // tanh
        float hnew = (1.f - z) * n + z * hp;
        _Float16 hv = (_Float16)hnew;
        h16[q] = __builtin_bit_cast(unsigned short, hv);
      }
      hc1.x = (unsigned)h16[0] | ((unsigned)h16[1] << 16);
      hc1.y = (unsigned)h16[2] | ((unsigned)h16[3] << 16);
      PKMAX(hm1.x, hc1.x);
      PKMAX(hm1.y, hc1.y);
      *(uint2*)&hT[(st + 1) & 1][nb][c01] = hc1;
    }
    __syncthreads();
  }

  // Output: out[b][dir*256 + c], b = bg*16 + nb. Unpack packed-f16 maxes.
  {
    float4 o = {h2f_(hm0.x, 0), h2f_(hm0.x, 1), h2f_(hm0.y, 0),
                h2f_(hm0.y, 1)};
    *(float4*)&out[(size_t)(bg * 16 + nb) * (2 * NH) + dir * NH + c00] = o;
    float4 p = {h2f_(hm1.x, 0), h2f_(hm1.x, 1), h2f_(hm1.y, 0),
                h2f_(hm1.y, 1)};
    *(float4*)&out[(size_t)(bg * 16 + nb) * (2 * NH) + dir * NH + c01] = p;
  }
}

// ---------------------------------------------------------------------------
extern "C" void kernel_launch(void* const* d_in, const int* in_sizes, int n_in,
                              void* d_out, int out_size, void* d_ws, size_t ws_size,
                              hipStream_t stream) {
  const int*   tokens = (const int*)d_in[0];
  const float* emb    = (const float*)d_in[1];
  const float* Wc     = (const float*)d_in[2];
  const float* bc     = (const float*)d_in[3];
  const float* Wih_f  = (const float*)d_in[4];
  const float* Whh_f  = (const float*)d_in[5];
  const float* bih_f  = (const float*)d_in[6];
  const float* bhh_f  = (const float*)d_in[7];
  const float* Wih_b  = (const float*)d_in[8];
  const float* Whh_b  = (const float*)d_in[9];
  const float* bih_b  = (const float*)d_in[10];
  const float* bhh_b  = (const float*)d_in[11];
  float* out = (float*)d_out;

  // Workspace (f32 units): P[50000*128] | enc[4096*128] | GIp (6.29M f16)
  //                        | Apk (49152 uint4)
  float* P   = (float*)d_ws;
  float* enc = P + (size_t)NV * NC;
  unsigned short* GIp = (unsigned short*)(enc + (size_t)NB * NL * NC);
  uint4* Apk = (uint4*)(GIp + (size_t)2 * 2 * 128 * 3 * 16 * 256);

  // 0) Pack Whh -> MFMA A-fragments.
  conv_w_pack<<<dim3(192), dim3(256), 0, stream>>>(Whh_f, Whh_b, Apk);
  // 1) P = emb @ Wc^T   (V x C)
  gemm_bt_k128<<<dim3((NV + 63) / 64, NC / 128), dim3(256), 0, stream>>>(
      emb, Wc, nullptr, P, NV, NC);
  // 2) tree encode -> enc (B*L x C)
  tree_encode<<<dim3(NB * NL), dim3(128), 0, stream>>>(tokens, P, bc, enc);
  // 3) GI f+b, f16 scan layout, bhh_r/z folded.
  gemm_gi<<<dim3(NB * NL / 64, G3 / 128, 2), dim3(256), 0, stream>>>(
      enc, Wih_f, Wih_b, bih_f, bih_b, bhh_f, bhh_b, GIp, NB * NL, G3);
  // 4) GRU scan v13 — named-SSA register-resident W.
  gru_scan_v13<<<dim3(4), dim3(512), 0, stream>>>(
      Apk, GIp, bhh_f, bhh_b, out);
}

// Round 14
// 378.054 us; speedup vs baseline: 1.8278x; 1.1091x over previous
//
#include <hip/hip_runtime.h>
#include <hip/hip_bf16.h>
#include <hip/hip_fp16.h>
#include <math.h>

// Problem constants: B=32, L=128, D=6, T=63, V=50000, E=C=128, H=256
#define NV 50000
#define NC 128
#define NH 256
#define NB 32
#define NL 128
#define NT 63
#define G3 768   // 3*H

typedef _Float16 f16x8 __attribute__((ext_vector_type(8)));
typedef _Float16 f16x2 __attribute__((ext_vector_type(2)));
typedef float f32x4 __attribute__((ext_vector_type(4)));

__device__ __forceinline__ float h2f_(unsigned int u, int hi) {
  f16x2 p = __builtin_bit_cast(f16x2, u);
  return (float)p[hi];
}

// ---------------------------------------------------------------------------
// C[m][n] = sum_k A[m][k]*B[n][k] (+bias), K=128, f32 out (for P = emb@Wc^T).
// ---------------------------------------------------------------------------
__global__ __launch_bounds__(256) void gemm_bt_k128(
    const float* __restrict__ A, const float* __restrict__ Bm,
    const float* __restrict__ bias, float* __restrict__ Cm,
    int M, int N) {
  __shared__ __align__(16) float As[64 * 129];
  __shared__ __align__(16) float BsT[64 * 132];  // [kk][n], one k-half
  const int m0 = blockIdx.x * 64;
  const int n0 = blockIdx.y * 128;
  const int tid = threadIdx.x;

#pragma unroll
  for (int i = 0; i < 32; ++i) {
    int e = tid + i * 256;
    int r = e >> 7, k = e & 127;
    int m = m0 + r;
    As[r * 129 + k] = (m < M) ? A[(size_t)m * 128 + k] : 0.0f;
  }

  const int tn = tid & 15;
  const int tm = tid >> 4;
  const int ml = tm * 4, nl = tn * 8;

  float acc[4][8];
#pragma unroll
  for (int i = 0; i < 4; ++i)
#pragma unroll
    for (int j = 0; j < 8; ++j) acc[i][j] = 0.0f;

#pragma unroll
  for (int h = 0; h < 2; ++h) {
    if (h) __syncthreads();
#pragma unroll
    for (int i = 0; i < 32; ++i) {
      int e = tid + i * 256;
      int n = e >> 6, kk = e & 63;
      BsT[kk * 132 + n] = Bm[(size_t)(n0 + n) * 128 + h * 64 + kk];
    }
    __syncthreads();
#pragma unroll 4
    for (int kk = 0; kk < 64; ++kk) {
      const int k = h * 64 + kk;
      float a0 = As[(ml + 0) * 129 + k];
      float a1 = As[(ml + 1) * 129 + k];
      float a2 = As[(ml + 2) * 129 + k];
      float a3 = As[(ml + 3) * 129 + k];
      float4 b0 = *(const float4*)&BsT[kk * 132 + nl];
      float4 b1 = *(const float4*)&BsT[kk * 132 + nl + 4];
      const float bv[8] = {b0.x, b0.y, b0.z, b0.w, b1.x, b1.y, b1.z, b1.w};
#pragma unroll
      for (int j = 0; j < 8; ++j) {
        acc[0][j] = fmaf(a0, bv[j], acc[0][j]);
        acc[1][j] = fmaf(a1, bv[j], acc[1][j]);
        acc[2][j] = fmaf(a2, bv[j], acc[2][j]);
        acc[3][j] = fmaf(a3, bv[j], acc[3][j]);
      }
    }
  }

  float bv[8];
#pragma unroll
  for (int j = 0; j < 8; ++j) bv[j] = bias ? bias[n0 + nl + j] : 0.0f;

#pragma unroll
  for (int i = 0; i < 4; ++i) {
    int m = m0 + ml + i;
    if (m < M) {
      float* crow = &Cm[(size_t)m * N + n0 + nl];
#pragma unroll
      for (int j = 0; j < 8; ++j) crow[j] = acc[i][j] + bv[j];
    }
  }
}

// ---------------------------------------------------------------------------
// GI GEMM -> plane-packed f16 layout for the v14 scan:
// For n = g*256 + c: s=(c>>4)&1, wv=c>>5, e=s*3+g, plane p=e>>1,
// byteoff=(e&1)*8; lg=(c>>2)&3, lane=lg*16+nb, tid=wv*64+lane.
// uint4 index: ((dirbg*3 + p)*128 + t)*512 + tid  (dirbg = dir*2+bg).
// bias = bih + bhh for the r,z gates (n<512), folded.
// ---------------------------------------------------------------------------
__global__ __launch_bounds__(256) void gemm_gi(
    const float* __restrict__ A,
    const float* __restrict__ B0, const float* __restrict__ B1,
    const float* __restrict__ bias0, const float* __restrict__ bias1,
    const float* __restrict__ bh0, const float* __restrict__ bh1,
    char* __restrict__ GIp2, int M, int N) {
  const float* __restrict__ Bm = blockIdx.z ? B1 : B0;
  const float* __restrict__ bias = blockIdx.z ? bias1 : bias0;
  const float* __restrict__ bh = blockIdx.z ? bh1 : bh0;

  __shared__ __align__(16) float As[64 * 129];
  __shared__ __align__(16) float BsT[64 * 132];
  const int m0 = blockIdx.x * 64;
  const int n0 = blockIdx.y * 128;
  const int tid = threadIdx.x;

#pragma unroll
  for (int i = 0; i < 32; ++i) {
    int e = tid + i * 256;
    int r = e >> 7, k = e & 127;
    int m = m0 + r;
    As[r * 129 + k] = (m < M) ? A[(size_t)m * 128 + k] : 0.0f;
  }

  const int tn = tid & 15;
  const int tm = tid >> 4;
  const int ml = tm * 4, nl = tn * 8;

  float acc[4][8];
#pragma unroll
  for (int i = 0; i < 4; ++i)
#pragma unroll
    for (int j = 0; j < 8; ++j) acc[i][j] = 0.0f;

#pragma unroll
  for (int h = 0; h < 2; ++h) {
    if (h) __syncthreads();
#pragma unroll
    for (int i = 0; i < 32; ++i) {
      int e = tid + i * 256;
      int n = e >> 6, kk = e & 63;
      BsT[kk * 132 + n] = Bm[(size_t)(n0 + n) * 128 + h * 64 + kk];
    }
    __syncthreads();
#pragma unroll 4
    for (int kk = 0; kk < 64; ++kk) {
      const int k = h * 64 + kk;
      float a0 = As[(ml + 0) * 129 + k];
      float a1 = As[(ml + 1) * 129 + k];
      float a2 = As[(ml + 2) * 129 + k];
      float a3 = As[(ml + 3) * 129 + k];
      float4 b0 = *(const float4*)&BsT[kk * 132 + nl];
      float4 b1 = *(const float4*)&BsT[kk * 132 + nl + 4];
      const float bv[8] = {b0.x, b0.y, b0.z, b0.w, b1.x, b1.y, b1.z, b1.w};
#pragma unroll
      for (int j = 0; j < 8; ++j) {
        acc[0][j] = fmaf(a0, bv[j], acc[0][j]);
        acc[1][j] = fmaf(a1, bv[j], acc[1][j]);
        acc[2][j] = fmaf(a2, bv[j], acc[2][j]);
        acc[3][j] = fmaf(a3, bv[j], acc[3][j]);
      }
    }
  }

  float bv[8];
#pragma unroll
  for (int j = 0; j < 8; ++j) {
    const int n = n0 + nl + j;
    bv[j] = bias[n] + (n < 512 ? bh[n] : 0.0f);  // fold bhh_r, bhh_z
  }

  const int ncol = n0 + nl;          // multiple of 8
  const int g = ncol >> 8;
  const int c0c = ncol & 255;
  const int s = (c0c >> 4) & 1;
  const int wv = c0c >> 5;
  const int e = s * 3 + g;
  const int p = e >> 1;
  const int byteoff = (e & 1) * 8;
#pragma unroll
  for (int i = 0; i < 4; ++i) {
    int m = m0 + ml + i;
    if (m < M) {
      int b = m >> 7, t = m & 127;
      int bg = b >> 4, nb = b & 15;
      int dirbg = blockIdx.z * 2 + bg;
#pragma unroll
      for (int half = 0; half < 2; ++half) {
        const int c_blk = c0c + half * 4;
        const int lg = (c_blk >> 2) & 3;
        const int tid_s = wv * 64 + lg * 16 + nb;
        size_t idx = (((size_t)(dirbg * 3 + p) * 128 + t) * 512 + tid_s);
        unsigned short hs[4];
#pragma unroll
        for (int k = 0; k < 4; ++k) {
          _Float16 hv = (_Float16)(acc[i][half * 4 + k] + bv[half * 4 + k]);
          hs[k] = __builtin_bit_cast(unsigned short, hv);
        }
        uint2 ov;
        ov.x = (unsigned)hs[0] | ((unsigned)hs[1] << 16);
        ov.y = (unsigned)hs[2] | ((unsigned)hs[3] << 16);
        *(uint2*)(GIp2 + idx * 16 + byteoff) = ov;
      }
    }
  }
}

// ---------------------------------------------------------------------------
// Tree encode: per (b,l), heap-sum P[tok], + cnt*bc, max, relu.
// ---------------------------------------------------------------------------
__global__ __launch_bounds__(128) void tree_encode(
    const int* __restrict__ tokens, const float* __restrict__ P,
    const float* __restrict__ bc, float* __restrict__ enc) {
  __shared__ int toks[NT];
  const int blk = blockIdx.x;
  const int c = threadIdx.x;
  if (c < NT) toks[c] = tokens[(size_t)blk * NT + c];
  __syncthreads();

  float s[NT];
#pragma unroll
  for (int i = 0; i < NT; ++i) s[i] = P[(size_t)toks[i] * NC + c];
#pragma unroll
  for (int i = 30; i >= 0; --i) s[i] += s[2 * i + 1] + s[2 * i + 2];

  const float bcv = bc[c];
  float m = -1e30f;
#pragma unroll
  for (int i = 0; i < NT; ++i) {
    const float cnt = (i == 0) ? 63.0f
                    : (i < 3)  ? 31.0f
                    : (i < 7)  ? 15.0f
                    : (i < 15) ? 7.0f
                    : (i < 31) ? 3.0f
                               : 1.0f;
    m = fmaxf(m, s[i] + cnt * bcv);
  }
  enc[(size_t)blk * NC + c] = fmaxf(m, 0.0f);
}

// ---------------------------------------------------------------------------
// Pack Whh f32 [768][256] -> MFMA A-fragments (f16), LAYOUT VERIFIED in R8:
//   Apk[(((dir*16 + cs)*3 + mt)*8 + ks)*64 + lane]:
//     Wrow = 16*cs + 256*mt + (lane&15),  k(j) = ks*32 + (lane>>4)*8 + j
// ---------------------------------------------------------------------------
__global__ __launch_bounds__(256) void conv_w_pack(
    const float* __restrict__ Wf, const float* __restrict__ Wb,
    uint4* __restrict__ Apk) {
  int i = blockIdx.x * 256 + threadIdx.x;  // [0, 2*16*3*8*64)
  if (i >= 2 * 16 * 3 * 8 * 64) return;
  const int dir = i / 24576;
  int rem = i - dir * 24576;
  const int cs = rem / 1536; rem -= cs * 1536;
  const int mt = rem / 512; rem -= mt * 512;
  const int ks = rem >> 6;
  const int lane = rem & 63;
  const int Wrow = 16 * cs + 256 * mt + (lane & 15);
  const int k0 = ks * 32 + ((lane >> 4) << 3);
  const float* __restrict__ W = dir ? Wb : Wf;
  const float4 a = *(const float4*)&W[(size_t)Wrow * NH + k0];
  const float4 b = *(const float4*)&W[(size_t)Wrow * NH + k0 + 4];
  const float v[8] = {a.x, a.y, a.z, a.w, b.x, b.y, b.z, b.w};
  unsigned short hs[8];
#pragma unroll
  for (int j = 0; j < 8; ++j) {
    _Float16 hv = (_Float16)v[j];
    hs[j] = __builtin_bit_cast(unsigned short, hv);
  }
  uint4 o;
  o.x = (unsigned)hs[0] | ((unsigned)hs[1] << 16);
  o.y = (unsigned)hs[2] | ((unsigned)hs[3] << 16);
  o.z = (unsigned)hs[4] | ((unsigned)hs[5] << 16);
  o.w = (unsigned)hs[6] | ((unsigned)hs[7] << 16);
  Apk[i] = o;
}

// ---------------------------------------------------------------------------
// GRU scan v14 = v13 (named-SSA resident W) + gi PREFETCH via
// global_load_lds one full step ahead (gi was consumed in-step in v13:
// every load a cold L3/HBM miss, ~2x900cy/step exposed at 2 waves/SIMD).
// gi packed per-thread-contiguous in 3 planes; per step each wave issues
// 3 fire-and-forget 16B/lane loads into double-buffered LDS; the end-of-
// step barrier's vmcnt drain guarantees availability next step. h kept in
// single-buffer LDS (read-all -> barrier -> write -> barrier); hp re-read
// from LDS to free registers. Peak regs ~250 <= 256.
// ---------------------------------------------------------------------------
#define WLOAD(q)                                                              \
  Apk[((((size_t)dir * 16 + (2 * w + ((q) / 24))) * 3 + (((q) / 8) % 3)) * 8 + \
       ((q)&7)) * 64 + lane]
#define WDECL(n)                                                              \
  uint4 w##n = WLOAD(n);                                                      \
  asm volatile("" : "+v"(w##n.x), "+v"(w##n.y), "+v"(w##n.z), "+v"(w##n.w));
#define KS(B, WR, WZ, WN)                                                     \
  {                                                                           \
    f16x8 bv_ = __builtin_bit_cast(f16x8, B);                                 \
    aR = __builtin_amdgcn_mfma_f32_16x16x32_f16(                              \
        __builtin_bit_cast(f16x8, WR), bv_, aR, 0, 0, 0);                     \
    aZ = __builtin_amdgcn_mfma_f32_16x16x32_f16(                              \
        __builtin_bit_cast(f16x8, WZ), bv_, aZ, 0, 0, 0);                     \
    aN = __builtin_amdgcn_mfma_f32_16x16x32_f16(                              \
        __builtin_bit_cast(f16x8, WN), bv_, aN, 0, 0, 0);                     \
  }
#define PKMAX(D, S)                                                           \
  asm("v_pk_max_f16 %0, %1, %2" : "=v"(D) : "v"(D), "v"(S))
#define GLOAD_LDS16(SRC, DST)                                                 \
  __builtin_amdgcn_global_load_lds(                                          \
      (const __attribute__((address_space(1))) void*)(SRC),                  \
      (__attribute__((address_space(3))) void*)(DST), 16, 0, 0)

__global__ __launch_bounds__(512, 2) void gru_scan_v14(
    const uint4* __restrict__ Apk, const char* __restrict__ GIp2,
    const float* __restrict__ bhh_f, const float* __restrict__ bhh_b,
    float* __restrict__ out) {
  const int dir = blockIdx.x >> 1;
  const int bg = blockIdx.x & 1;
  const int dirbg = dir * 2 + bg;
  const int tid = threadIdx.x;
  const int w = tid >> 6;      // wave [0,8)
  const int lane = tid & 63;
  const int lg = lane >> 4;
  const int nb = lane & 15;

  __shared__ __align__(16) unsigned short hT[16][264];   // single buffer
  __shared__ __align__(16) uint4 gilds[2][3][512];       // gi double buffer

  // ---- One-time W fill: 48 NAMED SSA values (v13-verified residency). ----
  WDECL(0)  WDECL(1)  WDECL(2)  WDECL(3)  WDECL(4)  WDECL(5)  WDECL(6)  WDECL(7)
  WDECL(8)  WDECL(9)  WDECL(10) WDECL(11) WDECL(12) WDECL(13) WDECL(14) WDECL(15)
  WDECL(16) WDECL(17) WDECL(18) WDECL(19) WDECL(20) WDECL(21) WDECL(22) WDECL(23)
  WDECL(24) WDECL(25) WDECL(26) WDECL(27) WDECL(28) WDECL(29) WDECL(30) WDECL(31)
  WDECL(32) WDECL(33) WDECL(34) WDECL(35) WDECL(36) WDECL(37) WDECL(38) WDECL(39)
  WDECL(40) WDECL(41) WDECL(42) WDECL(43) WDECL(44) WDECL(45) WDECL(46) WDECL(47)

  const float* __restrict__ bhh = dir ? bhh_b : bhh_f;
  const int c00 = (2 * w) * 16 + (lg << 2);
  const int c01 = c00 + 16;
  uint2 bn0, bn1;
  {
    float4 b4 = *(const float4*)&bhh[2 * NH + c00];
    _Float16 h0 = (_Float16)b4.x, h1 = (_Float16)b4.y;
    _Float16 h2 = (_Float16)b4.z, h3 = (_Float16)b4.w;
    bn0.x = (unsigned)__builtin_bit_cast(unsigned short, h0) |
            ((unsigned)__builtin_bit_cast(unsigned short, h1) << 16);
    bn0.y = (unsigned)__builtin_bit_cast(unsigned short, h2) |
            ((unsigned)__builtin_bit_cast(unsigned short, h3) << 16);
    float4 c4 = *(const float4*)&bhh[2 * NH + c01];
    _Float16 g0 = (_Float16)c4.x, g1 = (_Float16)c4.y;
    _Float16 g2 = (_Float16)c4.z, g3 = (_Float16)c4.w;
    bn1.x = (unsigned)__builtin_bit_cast(unsigned short, g0) |
            ((unsigned)__builtin_bit_cast(unsigned short, g1) << 16);
    bn1.y = (unsigned)__builtin_bit_cast(unsigned short, g2) |
            ((unsigned)__builtin_bit_cast(unsigned short, g3) << 16);
  }

  // Zero h buffer.
  for (int i = tid; i < 16 * 264 / 2; i += 512) ((unsigned int*)hT)[i] = 0u;

  const char* __restrict__ gbase =
      GIp2 + (size_t)dirbg * 3 * 128 * 512 * 16;

  // Prologue: prefetch gi for step 0 into gilds[0].
  {
    const int t0i = dir ? (NL - 1) : 0;
#pragma unroll
    for (int p = 0; p < 3; ++p) {
      const char* src = gbase + (((size_t)p * 128 + t0i) * 512 + tid) * 16;
      GLOAD_LDS16(src, &gilds[0][p][w * 64]);
    }
  }

  uint2 hm0 = {0xFC00FC00u, 0xFC00FC00u}, hm1 = {0xFC00FC00u, 0xFC00FC00u};
  __syncthreads();  // hT zero + prefetch drain

  for (int st = 0; st < NL; ++st) {
    // Prefetch next step's gi into the other LDS buffer (fire-and-forget).
    {
      const int stn = (st + 1 < NL) ? st + 1 : st;
      const int tn = dir ? (NL - 1 - stn) : stn;
#pragma unroll
      for (int p = 0; p < 3; ++p) {
        const char* src = gbase + (((size_t)p * 128 + tn) * 512 + tid) * 16;
        GLOAD_LDS16(src, &gilds[(st + 1) & 1][p][w * 64]);
      }
    }

    // Current gi (prefetched last step) + previous h for own channels.
    uint4 P0 = gilds[st & 1][0][tid];
    uint4 P1 = gilds[st & 1][1][tid];
    uint4 P2 = gilds[st & 1][2][tid];
    uint2 hp0 = *(const uint2*)&hT[nb][c00];
    uint2 hp1 = *(const uint2*)&hT[nb][c01];
    const unsigned short* __restrict__ hrow = &hT[nb][lg << 3];

    uint2 hc0, hc1;
    // ---------------- SET 0 ----------------
    {
      f32x4 aR = {0.f, 0.f, 0.f, 0.f};
      f32x4 aZ = {0.f, 0.f, 0.f, 0.f};
      f32x4 aN = {h2f_(bn0.x, 0), h2f_(bn0.x, 1), h2f_(bn0.y, 0),
                  h2f_(bn0.y, 1)};
      uint4 bA = *(const uint4*)(hrow + 0 * 32);
      uint4 bB = *(const uint4*)(hrow + 1 * 32);
      KS(bA, w0, w8, w16);  bA = *(const uint4*)(hrow + 2 * 32);
      KS(bB, w1, w9, w17);  bB = *(const uint4*)(hrow + 3 * 32);
      KS(bA, w2, w10, w18); bA = *(const uint4*)(hrow + 4 * 32);
      KS(bB, w3, w11, w19); bB = *(const uint4*)(hrow + 5 * 32);
      KS(bA, w4, w12, w20); bA = *(const uint4*)(hrow + 6 * 32);
      KS(bB, w5, w13, w21); bB = *(const uint4*)(hrow + 7 * 32);
      KS(bA, w6, w14, w22);
      KS(bB, w7, w15, w23);

      unsigned short h16[4];
#pragma unroll
      for (int q = 0; q < 4; ++q) {
        float gr = h2f_(q & 2 ? P0.y : P0.x, q & 1);
        float gz = h2f_(q & 2 ? P0.w : P0.z, q & 1);
        float gn = h2f_(q & 2 ? P1.y : P1.x, q & 1);
        float hp = h2f_(q & 2 ? hp0.y : hp0.x, q & 1);
        float r = __builtin_amdgcn_rcpf(1.f + __expf(-(gr + aR[q])));
        float z = __builtin_amdgcn_rcpf(1.f + __expf(-(gz + aZ[q])));
        float x = gn + r * aN[q];
        float e = __expf(-2.f * x);
        float n = 2.f * __builtin_amdgcn_rcpf(1.f + e) - 1.f;  // tanh
        float hnew = (1.f - z) * n + z * hp;
        _Float16 hv = (_Float16)hnew;
        h16[q] = __builtin_bit_cast(unsigned short, hv);
      }
      hc0.x = (unsigned)h16[0] | ((unsigned)h16[1] << 16);
      hc0.y = (unsigned)h16[2] | ((unsigned)h16[3] << 16);
      PKMAX(hm0.x, hc0.x);
      PKMAX(hm0.y, hc0.y);
    }
    // ---------------- SET 1 ----------------
    {
      f32x4 aR = {0.f, 0.f, 0.f, 0.f};
      f32x4 aZ = {0.f, 0.f, 0.f, 0.f};
      f32x4 aN = {h2f_(bn1.x, 0), h2f_(bn1.x, 1), h2f_(bn1.y, 0),
                  h2f_(bn1.y, 1)};
      uint4 bA = *(const uint4*)(hrow + 0 * 32);
      uint4 bB = *(const uint4*)(hrow + 1 * 32);
      KS(bA, w24, w32, w40); bA = *(const uint4*)(hrow + 2 * 32);
      KS(bB, w25, w33, w41); bB = *(const uint4*)(hrow + 3 * 32);
      KS(bA, w26, w34, w42); bA = *(const uint4*)(hrow + 4 * 32);
      KS(bB, w27, w35, w43); bB = *(const uint4*)(hrow + 5 * 32);
      KS(bA, w28, w36, w44); bA = *(const uint4*)(hrow + 6 * 32);
      KS(bB, w29, w37, w45); bB = *(const uint4*)(hrow + 7 * 32);
      KS(bA, w30, w38, w46);
      KS(bB, w31, w39, w47);

      unsigned short h16[4];
#pragma unroll
      for (int q = 0; q < 4; ++q) {
        float gr = h2f_(q & 2 ? P1.w : P1.z, q & 1);
        float gz = h2f_(q & 2 ? P2.y : P2.x, q & 1);
        float gn = h2f_(q & 2 ? P2.w : P2.z, q & 1);
        float hp = h2f_(q & 2 ? hp1.y : hp1.x, q & 1);
        float r = __builtin_amdgcn_rcpf(1.f + __expf(-(gr + aR[q])));
        float z = __builtin_amdgcn_rcpf(1.f + __expf(-(gz + aZ[q])));
        float x = gn + r * aN[q];
        float e = __expf(-2.f * x);
        float n = 2.f * __builtin_amdgcn_rcpf(1.f + e) - 1.f;  // tanh
        float hnew = (1.f - z) * n + z * hp;
        _Float16 hv = (_Float16)hnew;
        h16[q] = __builtin_bit_cast(unsigned short, hv);
      }
      hc1.x = (unsigned)h16[0] | ((unsigned)h16[1] << 16);
      hc1.y = (unsigned)h16[2] | ((unsigned)h16[3] << 16);
      PKMAX(hm1.x, hc1.x);
      PKMAX(hm1.y, hc1.y);
    }
    __syncthreads();  // all reads of old h done (also drains gi prefetch)
    *(uint2*)&hT[nb][c00] = hc0;
    *(uint2*)&hT[nb][c01] = hc1;
    __syncthreads();  // new h visible
  }

  // Output: out[b][dir*256 + c], b = bg*16 + nb.
  {
    float4 o = {h2f_(hm0.x, 0), h2f_(hm0.x, 1), h2f_(hm0.y, 0),
                h2f_(hm0.y, 1)};
    *(float4*)&out[(size_t)(bg * 16 + nb) * (2 * NH) + dir * NH + c00] = o;
    float4 p = {h2f_(hm1.x, 0), h2f_(hm1.x, 1), h2f_(hm1.y, 0),
                h2f_(hm1.y, 1)};
    *(float4*)&out[(size_t)(bg * 16 + nb) * (2 * NH) + dir * NH + c01] = p;
  }
}

// ---------------------------------------------------------------------------
extern "C" void kernel_launch(void* const* d_in, const int* in_sizes, int n_in,
                              void* d_out, int out_size, void* d_ws, size_t ws_size,
                              hipStream_t stream) {
  const int*   tokens = (const int*)d_in[0];
  const float* emb    = (const float*)d_in[1];
  const float* Wc     = (const float*)d_in[2];
  const float* bc     = (const float*)d_in[3];
  const float* Wih_f  = (const float*)d_in[4];
  const float* Whh_f  = (const float*)d_in[5];
  const float* bih_f  = (const float*)d_in[6];
  const float* bhh_f  = (const float*)d_in[7];
  const float* Wih_b  = (const float*)d_in[8];
  const float* Whh_b  = (const float*)d_in[9];
  const float* bih_b  = (const float*)d_in[10];
  const float* bhh_b  = (const float*)d_in[11];
  float* out = (float*)d_out;

  // Workspace (f32 units): P[50000*128] | enc[4096*128] | GIp2 (12.58MB)
  //                        | Apk (49152 uint4)
  float* P   = (float*)d_ws;
  float* enc = P + (size_t)NV * NC;
  char* GIp2 = (char*)(enc + (size_t)NB * NL * NC);
  uint4* Apk = (uint4*)(GIp2 + (size_t)4 * 3 * 128 * 512 * 16);

  // 0) Pack Whh -> MFMA A-fragments.
  conv_w_pack<<<dim3(192), dim3(256), 0, stream>>>(Whh_f, Whh_b, Apk);
  // 1) P = emb @ Wc^T   (V x C)
  gemm_bt_k128<<<dim3((NV + 63) / 64, NC / 128), dim3(256), 0, stream>>>(
      emb, Wc, nullptr, P, NV, NC);
  // 2) tree encode -> enc (B*L x C)
  tree_encode<<<dim3(NB * NL), dim3(128), 0, stream>>>(tokens, P, bc, enc);
  // 3) GI f+b, plane-packed f16 scan layout, bhh_r/z folded.
  gemm_gi<<<dim3(NB * NL / 64, G3 / 128, 2), dim3(256), 0, stream>>>(
      enc, Wih_f, Wih_b, bih_f, bih_b, bhh_f, bhh_b, GIp2, NB * NL, G3);
  // 4) GRU scan v14 — resident W + gi prefetch via global_load_lds.
  gru_scan_v14<<<dim3(4), dim3(512), 0, stream>>>(
      Apk, GIp2, bhh_f, bhh_b, out);
}